// Round 2
// baseline (6517.963 us; speedup 1.0000x reference)
//
#include <hip/hip_runtime.h>
#include <hip/hip_bf16.h>
#include <cstddef>

// ---------------- problem constants ----------------
#define NE 800000
// node types: 0=drug, 1=gene, 2=disease
// etypes: 0=treats(drug->disease) 1=targets(drug->gene) 2=assoc(gene->disease) 3=rev_treats(disease->drug)

__device__ __forceinline__ float lrelu01(float x) { return x > 0.f ? x : 0.01f * x; }

// ---------------- degree count (per-etype) ----------------
__global__ __launch_bounds__(256) void count_kernel(const int* __restrict__ dst,
                                                    int* __restrict__ cnt) {
  int stride = gridDim.x * blockDim.x;
  for (int i = blockIdx.x * blockDim.x + threadIdx.x; i < NE; i += stride)
    atomicAdd(&cnt[dst[i]], 1);
}

__global__ __launch_bounds__(256) void inv_kernel(const int* __restrict__ cnt,
                                                  float* __restrict__ inv, int n) {
  int i = blockIdx.x * blockDim.x + threadIdx.x;
  if (i < n) {
    int c = cnt[i];
    inv[i] = 1.0f / (float)(c > 1 ? c : 1);
  }
}

// ---------------- GEMM: out[n,:] = X[n,:] @ W + b  (K=N=128) ----------------
// block = 256 threads, 32 rows per block. W (64KB) + x-tile (16KB) in LDS.
template <bool LRELU>
__global__ __launch_bounds__(256) void gemm_kernel(const float* __restrict__ X,
                                                   const float* __restrict__ W,
                                                   const float* __restrict__ bias,
                                                   float* __restrict__ out, int nrows) {
  __shared__ float Ws[128 * 128];
  __shared__ float xs[32 * 128];
  const int tid = threadIdx.x;

  {  // stage W (16384 floats = 4096 float4; 256 threads x 16)
    const float4* Wv = (const float4*)W;
    float4* Wsv = (float4*)Ws;
#pragma unroll
    for (int i = 0; i < 16; ++i) Wsv[tid + 256 * i] = Wv[tid + 256 * i];
  }
  const int row0 = blockIdx.x * 32;
  {  // stage 32 rows of X: 32 rows * 32 float4/row = 1024 float4; 4 per thread
    float4* xsv = (float4*)xs;
#pragma unroll
    for (int i = 0; i < 4; ++i) {
      int f = tid + 256 * i;      // float4 index 0..1023
      int rr = f >> 5;            // row 0..31
      int c4 = f & 31;            // float4 col 0..31
      int gr = row0 + rr;
      float4 v = make_float4(0.f, 0.f, 0.f, 0.f);
      if (gr < nrows) v = *(const float4*)(X + (size_t)gr * 128 + c4 * 4);
      if (LRELU) {
        v.x = lrelu01(v.x); v.y = lrelu01(v.y); v.z = lrelu01(v.z); v.w = lrelu01(v.w);
      }
      xsv[f] = v;
    }
  }
  __syncthreads();

  const int c = tid & 31;   // columns 4c..4c+3
  const int r = tid >> 5;   // rows r, r+8, r+16, r+24
  const float4 bv = *(const float4*)(bias + c * 4);
  float acc[4][4];
#pragma unroll
  for (int ri = 0; ri < 4; ++ri) {
    acc[ri][0] = bv.x; acc[ri][1] = bv.y; acc[ri][2] = bv.z; acc[ri][3] = bv.w;
  }

#pragma unroll 8
  for (int k0 = 0; k0 < 128; k0 += 4) {
    const float4 w0 = *(const float4*)(Ws + (k0 + 0) * 128 + c * 4);
    const float4 w1 = *(const float4*)(Ws + (k0 + 1) * 128 + c * 4);
    const float4 w2 = *(const float4*)(Ws + (k0 + 2) * 128 + c * 4);
    const float4 w3 = *(const float4*)(Ws + (k0 + 3) * 128 + c * 4);
#pragma unroll
    for (int ri = 0; ri < 4; ++ri) {
      const float4 xv = *(const float4*)(xs + (r + 8 * ri) * 128 + k0);
      acc[ri][0] = fmaf(xv.x, w0.x, acc[ri][0]);
      acc[ri][0] = fmaf(xv.y, w1.x, acc[ri][0]);
      acc[ri][0] = fmaf(xv.z, w2.x, acc[ri][0]);
      acc[ri][0] = fmaf(xv.w, w3.x, acc[ri][0]);
      acc[ri][1] = fmaf(xv.x, w0.y, acc[ri][1]);
      acc[ri][1] = fmaf(xv.y, w1.y, acc[ri][1]);
      acc[ri][1] = fmaf(xv.z, w2.y, acc[ri][1]);
      acc[ri][1] = fmaf(xv.w, w3.y, acc[ri][1]);
      acc[ri][2] = fmaf(xv.x, w0.z, acc[ri][2]);
      acc[ri][2] = fmaf(xv.y, w1.z, acc[ri][2]);
      acc[ri][2] = fmaf(xv.z, w2.z, acc[ri][2]);
      acc[ri][2] = fmaf(xv.w, w3.z, acc[ri][2]);
      acc[ri][3] = fmaf(xv.x, w0.w, acc[ri][3]);
      acc[ri][3] = fmaf(xv.y, w1.w, acc[ri][3]);
      acc[ri][3] = fmaf(xv.z, w2.w, acc[ri][3]);
      acc[ri][3] = fmaf(xv.w, w3.w, acc[ri][3]);
    }
  }

#pragma unroll
  for (int ri = 0; ri < 4; ++ri) {
    int gr = row0 + r + 8 * ri;
    if (gr < nrows) {
      float4 o = make_float4(acc[ri][0], acc[ri][1], acc[ri][2], acc[ri][3]);
      *(float4*)(out + (size_t)gr * 128 + c * 4) = o;
    }
  }
}

// ---------------- scatter: out[dst] += Wh[src] * inv_cnt[dst] (atomic) ----------------
__global__ __launch_bounds__(256) void scatter_kernel(const float* __restrict__ Wh,
                                                      const int* __restrict__ src,
                                                      const int* __restrict__ dst,
                                                      const float* __restrict__ inv,
                                                      float* __restrict__ out) {
  const int lane = threadIdx.x & 63;
  int wid = (blockIdx.x * blockDim.x + threadIdx.x) >> 6;
  const int nw = (gridDim.x * blockDim.x) >> 6;
  for (int e = wid; e < NE; e += nw) {
    int s = src[e];
    int d = dst[e];
    float ic = inv[d];
    float2 v = *(const float2*)(Wh + (size_t)s * 128 + lane * 2);
    float* o = out + (size_t)d * 128 + lane * 2;
    atomicAdd(o, v.x * ic);
    atomicAdd(o + 1, v.y * ic);
  }
}

// ---------------- scores: sigmoid(h_s[src].h_d[dst]) and sigmoid(h_s[src].h_d[ndst]) ----------------
__global__ __launch_bounds__(256) void score_kernel(const float* __restrict__ hs,
                                                    const float* __restrict__ hd,
                                                    const int* __restrict__ src,
                                                    const int* __restrict__ dst,
                                                    const int* __restrict__ ndst,
                                                    float* __restrict__ outp,
                                                    float* __restrict__ outn) {
  const int lane = threadIdx.x & 63;
  int wid = (blockIdx.x * blockDim.x + threadIdx.x) >> 6;
  const int nw = (gridDim.x * blockDim.x) >> 6;
  for (int e = wid; e < NE; e += nw) {
    int s = src[e], d = dst[e], n = ndst[e];
    float2 a = *(const float2*)(hs + (size_t)s * 128 + lane * 2);
    float2 b = *(const float2*)(hd + (size_t)d * 128 + lane * 2);
    float2 cgt = *(const float2*)(hd + (size_t)n * 128 + lane * 2);
    float dp = a.x * b.x + a.y * b.y;
    float dn = a.x * cgt.x + a.y * cgt.y;
#pragma unroll
    for (int off = 32; off >= 1; off >>= 1) {
      dp += __shfl_xor(dp, off, 64);
      dn += __shfl_xor(dn, off, 64);
    }
    if (lane == 0) {
      outp[e] = 1.0f / (1.0f + expf(-dp));
      outn[e] = 1.0f / (1.0f + expf(-dn));
    }
  }
}

// ---------------- launch ----------------
extern "C" void kernel_launch(void* const* d_in, const int* in_sizes, int n_in,
                              void* d_out, int out_size, void* d_ws, size_t ws_size,
                              hipStream_t stream) {
  const float* feat[3] = {(const float*)d_in[0], (const float*)d_in[1], (const float*)d_in[2]};
  const float *W1[4], *b1[4], *W2[4], *b2[4];
  for (int e = 0; e < 4; ++e) {
    W1[e] = (const float*)d_in[3 + 2 * e];
    b1[e] = (const float*)d_in[4 + 2 * e];
    W2[e] = (const float*)d_in[11 + 2 * e];
    b2[e] = (const float*)d_in[12 + 2 * e];
  }
  const int *src[4], *dst[4], *ndst[4];
  for (int e = 0; e < 4; ++e) {
    src[e] = (const int*)d_in[19 + 3 * e];
    dst[e] = (const int*)d_in[20 + 3 * e];
    ndst[e] = (const int*)d_in[21 + 3 * e];
  }

  // workspace carve-up
  float* Wh = (float*)d_ws;                       // 80000*128 f32 = 40.96 MB
  float* h1 = Wh + (size_t)80000 * 128;           // 120000*128 f32 = 61.44 MB
  float* h2 = h1 + (size_t)120000 * 128;          // 61.44 MB
  int* cnt = (int*)(h2 + (size_t)120000 * 128);   // 140000 ints
  float* inv = (float*)(cnt + 140000);            // 140000 f32

  hipMemsetAsync(h1, 0, (size_t)120000 * 128 * 4, stream);
  hipMemsetAsync(h2, 0, (size_t)120000 * 128 * 4, stream);
  hipMemsetAsync(cnt, 0, (size_t)140000 * 4, stream);

  const int styp[4] = {0, 0, 1, 2};
  const int dtyp[4] = {2, 1, 2, 0};
  const size_t hoff[3] = {0, 20000, 100000};  // row offsets: drug, gene, disease
  const int coff[4] = {0, 20000, 100000, 120000};
  const int Nn[3] = {20000, 80000, 20000};

  // degree counts (same for both layers) -> inverse
  for (int e = 0; e < 4; ++e)
    count_kernel<<<512, 256, 0, stream>>>(dst[e], cnt + coff[e]);
  inv_kernel<<<(140000 + 255) / 256, 256, 0, stream>>>(cnt, inv, 140000);

  // layer 1
  for (int e = 0; e < 4; ++e) {
    int ns = Nn[styp[e]];
    gemm_kernel<false><<<ns / 32, 256, 0, stream>>>(feat[styp[e]], W1[e], b1[e], Wh, ns);
    scatter_kernel<<<2048, 256, 0, stream>>>(Wh, src[e], dst[e], inv + coff[e],
                                             h1 + hoff[dtyp[e]] * 128);
  }
  // layer 2 (leaky-relu fused into x load)
  for (int e = 0; e < 4; ++e) {
    int ns = Nn[styp[e]];
    gemm_kernel<true><<<ns / 32, 256, 0, stream>>>(h1 + hoff[styp[e]] * 128, W2[e], b2[e], Wh, ns);
    scatter_kernel<<<2048, 256, 0, stream>>>(Wh, src[e], dst[e], inv + coff[e],
                                             h2 + hoff[dtyp[e]] * 128);
  }
  // scores (pos + neg fused per etype)
  float* out = (float*)d_out;
  for (int e = 0; e < 4; ++e) {
    score_kernel<<<2048, 256, 0, stream>>>(h2 + hoff[styp[e]] * 128, h2 + hoff[dtyp[e]] * 128,
                                           src[e], dst[e], ndst[e], out + (size_t)e * NE,
                                           out + (size_t)(4 + e) * NE);
  }
}

// Round 3
// 2080.422 us; speedup vs baseline: 3.1330x; 3.1330x over previous
//
#include <hip/hip_runtime.h>
#include <hip/hip_bf16.h>
#include <cstddef>

// ---------------- problem constants ----------------
#define NE 800000
// node types: 0=drug, 1=gene, 2=disease
// etypes: 0=treats(drug->disease) 1=targets(drug->gene) 2=assoc(gene->disease) 3=rev_treats(disease->drug)

__device__ __forceinline__ float lrelu01(float x) { return x > 0.f ? x : 0.01f * x; }

// ---------------- degree count (per-etype) ----------------
__global__ __launch_bounds__(256) void count_kernel(const int* __restrict__ dst,
                                                    int* __restrict__ cnt) {
  int stride = gridDim.x * blockDim.x;
  for (int i = blockIdx.x * blockDim.x + threadIdx.x; i < NE; i += stride)
    atomicAdd(&cnt[dst[i]], 1);
}

__global__ __launch_bounds__(256) void inv_kernel(const int* __restrict__ cnt,
                                                  float* __restrict__ inv, int n) {
  int i = blockIdx.x * blockDim.x + threadIdx.x;
  if (i < n) {
    int c = cnt[i];
    inv[i] = 1.0f / (float)(c > 1 ? c : 1);
  }
}

// ---------------- exclusive scan (single workgroup, n <= ~100k) ----------------
__global__ __launch_bounds__(1024) void scan_kernel(const int* __restrict__ cnt,
                                                    int* __restrict__ rowptr, int n) {
  __shared__ int sums[1024];
  const int tid = threadIdx.x;
  const int per = (n + 1023) >> 10;
  const int beg = tid * per;
  const int end = min(beg + per, n);
  int s = 0;
  for (int i = beg; i < end; ++i) s += cnt[i];
  sums[tid] = s;
  __syncthreads();
  // Hillis-Steele inclusive scan over 1024 partials
  for (int off = 1; off < 1024; off <<= 1) {
    int add = (tid >= off) ? sums[tid - off] : 0;
    __syncthreads();
    sums[tid] += add;
    __syncthreads();
  }
  int run = (tid == 0) ? 0 : sums[tid - 1];
  for (int i = beg; i < end; ++i) {
    rowptr[i] = run;
    run += cnt[i];
  }
  if (tid == 1023) rowptr[n] = sums[1023];
}

// ---------------- CSR placement: csr[rowptr[d] + pos++] = src ----------------
__global__ __launch_bounds__(256) void place_kernel(const int* __restrict__ src,
                                                    const int* __restrict__ dst,
                                                    const int* __restrict__ rowptr,
                                                    int* __restrict__ cursor,
                                                    int* __restrict__ csr) {
  int stride = gridDim.x * blockDim.x;
  for (int i = blockIdx.x * blockDim.x + threadIdx.x; i < NE; i += stride) {
    int d = dst[i];
    int p = rowptr[d] + atomicAdd(&cursor[d], 1);
    csr[p] = src[i];
  }
}

// ---------------- GEMM: out[n,:] = X[n,:] @ W + b  (K=N=128) ----------------
template <bool LRELU>
__global__ __launch_bounds__(256) void gemm_kernel(const float* __restrict__ X,
                                                   const float* __restrict__ W,
                                                   const float* __restrict__ bias,
                                                   float* __restrict__ out, int nrows) {
  __shared__ float Ws[128 * 128];
  __shared__ float xs[32 * 128];
  const int tid = threadIdx.x;

  {  // stage W (16384 floats = 4096 float4; 256 threads x 16)
    const float4* Wv = (const float4*)W;
    float4* Wsv = (float4*)Ws;
#pragma unroll
    for (int i = 0; i < 16; ++i) Wsv[tid + 256 * i] = Wv[tid + 256 * i];
  }
  const int row0 = blockIdx.x * 32;
  {  // stage 32 rows of X: 1024 float4; 4 per thread
    float4* xsv = (float4*)xs;
#pragma unroll
    for (int i = 0; i < 4; ++i) {
      int f = tid + 256 * i;
      int rr = f >> 5;
      int c4 = f & 31;
      int gr = row0 + rr;
      float4 v = make_float4(0.f, 0.f, 0.f, 0.f);
      if (gr < nrows) v = *(const float4*)(X + (size_t)gr * 128 + c4 * 4);
      if (LRELU) {
        v.x = lrelu01(v.x); v.y = lrelu01(v.y); v.z = lrelu01(v.z); v.w = lrelu01(v.w);
      }
      xsv[f] = v;
    }
  }
  __syncthreads();

  const int c = tid & 31;
  const int r = tid >> 5;
  const float4 bv = *(const float4*)(bias + c * 4);
  float acc[4][4];
#pragma unroll
  for (int ri = 0; ri < 4; ++ri) {
    acc[ri][0] = bv.x; acc[ri][1] = bv.y; acc[ri][2] = bv.z; acc[ri][3] = bv.w;
  }

#pragma unroll 8
  for (int k0 = 0; k0 < 128; k0 += 4) {
    const float4 w0 = *(const float4*)(Ws + (k0 + 0) * 128 + c * 4);
    const float4 w1 = *(const float4*)(Ws + (k0 + 1) * 128 + c * 4);
    const float4 w2 = *(const float4*)(Ws + (k0 + 2) * 128 + c * 4);
    const float4 w3 = *(const float4*)(Ws + (k0 + 3) * 128 + c * 4);
#pragma unroll
    for (int ri = 0; ri < 4; ++ri) {
      const float4 xv = *(const float4*)(xs + (r + 8 * ri) * 128 + k0);
      acc[ri][0] = fmaf(xv.x, w0.x, acc[ri][0]);
      acc[ri][0] = fmaf(xv.y, w1.x, acc[ri][0]);
      acc[ri][0] = fmaf(xv.z, w2.x, acc[ri][0]);
      acc[ri][0] = fmaf(xv.w, w3.x, acc[ri][0]);
      acc[ri][1] = fmaf(xv.x, w0.y, acc[ri][1]);
      acc[ri][1] = fmaf(xv.y, w1.y, acc[ri][1]);
      acc[ri][1] = fmaf(xv.z, w2.y, acc[ri][1]);
      acc[ri][1] = fmaf(xv.w, w3.y, acc[ri][1]);
      acc[ri][2] = fmaf(xv.x, w0.z, acc[ri][2]);
      acc[ri][2] = fmaf(xv.y, w1.z, acc[ri][2]);
      acc[ri][2] = fmaf(xv.z, w2.z, acc[ri][2]);
      acc[ri][2] = fmaf(xv.w, w3.z, acc[ri][2]);
      acc[ri][3] = fmaf(xv.x, w0.w, acc[ri][3]);
      acc[ri][3] = fmaf(xv.y, w1.w, acc[ri][3]);
      acc[ri][3] = fmaf(xv.z, w2.w, acc[ri][3]);
      acc[ri][3] = fmaf(xv.w, w3.w, acc[ri][3]);
    }
  }

#pragma unroll
  for (int ri = 0; ri < 4; ++ri) {
    int gr = row0 + r + 8 * ri;
    if (gr < nrows) {
      float4 o = make_float4(acc[ri][0], acc[ri][1], acc[ri][2], acc[ri][3]);
      *(float4*)(out + (size_t)gr * 128 + c * 4) = o;
    }
  }
}

// ---------------- CSR aggregate: out[d] += inv[d] * sum_{e in row d} Wh[csr[e]] ----------------
// one wave per dst node; 64-index coalesced batch + shfl broadcast; float2 per lane
__global__ __launch_bounds__(256) void gather_kernel(const float* __restrict__ Wh,
                                                     const int* __restrict__ csr,
                                                     const int* __restrict__ rowptr,
                                                     const float* __restrict__ inv,
                                                     float* __restrict__ out, int nd) {
  const int lane = threadIdx.x & 63;
  int w = (blockIdx.x * blockDim.x + threadIdx.x) >> 6;
  const int nw = (gridDim.x * blockDim.x) >> 6;
  for (int d = w; d < nd; d += nw) {
    const int beg = rowptr[d];
    const int end = rowptr[d + 1];
    float ax = 0.f, ay = 0.f;
    for (int c0 = beg; c0 < end; c0 += 64) {
      int m = end - c0;
      if (m > 64) m = 64;
      int idx = (c0 + lane < end) ? csr[c0 + lane] : 0;
      int j = 0;
      for (; j + 4 <= m; j += 4) {
        int s0 = __shfl(idx, j, 64);
        int s1 = __shfl(idx, j + 1, 64);
        int s2 = __shfl(idx, j + 2, 64);
        int s3 = __shfl(idx, j + 3, 64);
        float2 v0 = *(const float2*)(Wh + (size_t)s0 * 128 + lane * 2);
        float2 v1 = *(const float2*)(Wh + (size_t)s1 * 128 + lane * 2);
        float2 v2 = *(const float2*)(Wh + (size_t)s2 * 128 + lane * 2);
        float2 v3 = *(const float2*)(Wh + (size_t)s3 * 128 + lane * 2);
        ax += v0.x + v1.x + v2.x + v3.x;
        ay += v0.y + v1.y + v2.y + v3.y;
      }
      for (; j < m; ++j) {
        int s = __shfl(idx, j, 64);
        float2 v = *(const float2*)(Wh + (size_t)s * 128 + lane * 2);
        ax += v.x;
        ay += v.y;
      }
    }
    float ic = inv[d];
    float2 o = *(float2*)(out + (size_t)d * 128 + lane * 2);
    o.x += ax * ic;
    o.y += ay * ic;
    *(float2*)(out + (size_t)d * 128 + lane * 2) = o;
  }
}

// ---------------- scores: sigmoid(h_s[src].h_d[dst]) and sigmoid(h_s[src].h_d[ndst]) ----------------
__global__ __launch_bounds__(256) void score_kernel(const float* __restrict__ hs,
                                                    const float* __restrict__ hd,
                                                    const int* __restrict__ src,
                                                    const int* __restrict__ dst,
                                                    const int* __restrict__ ndst,
                                                    float* __restrict__ outp,
                                                    float* __restrict__ outn) {
  const int lane = threadIdx.x & 63;
  int wid = (blockIdx.x * blockDim.x + threadIdx.x) >> 6;
  const int nw = (gridDim.x * blockDim.x) >> 6;
  for (int e = wid; e < NE; e += nw) {
    int s = src[e], d = dst[e], n = ndst[e];
    float2 a = *(const float2*)(hs + (size_t)s * 128 + lane * 2);
    float2 b = *(const float2*)(hd + (size_t)d * 128 + lane * 2);
    float2 cgt = *(const float2*)(hd + (size_t)n * 128 + lane * 2);
    float dp = a.x * b.x + a.y * b.y;
    float dn = a.x * cgt.x + a.y * cgt.y;
#pragma unroll
    for (int off = 32; off >= 1; off >>= 1) {
      dp += __shfl_xor(dp, off, 64);
      dn += __shfl_xor(dn, off, 64);
    }
    if (lane == 0) {
      outp[e] = 1.0f / (1.0f + expf(-dp));
      outn[e] = 1.0f / (1.0f + expf(-dn));
    }
  }
}

// ---------------- launch ----------------
extern "C" void kernel_launch(void* const* d_in, const int* in_sizes, int n_in,
                              void* d_out, int out_size, void* d_ws, size_t ws_size,
                              hipStream_t stream) {
  const float* feat[3] = {(const float*)d_in[0], (const float*)d_in[1], (const float*)d_in[2]};
  const float *W1[4], *b1[4], *W2[4], *b2[4];
  for (int e = 0; e < 4; ++e) {
    W1[e] = (const float*)d_in[3 + 2 * e];
    b1[e] = (const float*)d_in[4 + 2 * e];
    W2[e] = (const float*)d_in[11 + 2 * e];
    b2[e] = (const float*)d_in[12 + 2 * e];
  }
  const int *src[4], *dst[4], *ndst[4];
  for (int e = 0; e < 4; ++e) {
    src[e] = (const int*)d_in[19 + 3 * e];
    dst[e] = (const int*)d_in[20 + 3 * e];
    ndst[e] = (const int*)d_in[21 + 3 * e];
  }

  // workspace carve-up
  float* Wh = (float*)d_ws;                        // 80000*128 f32 = 40.96 MB
  float* h1 = Wh + (size_t)80000 * 128;            // 120000*128 f32 = 61.44 MB
  float* h2 = h1 + (size_t)120000 * 128;           // 61.44 MB
  int* cnt = (int*)(h2 + (size_t)120000 * 128);    // 140000
  float* inv = (float*)(cnt + 140000);             // 140000
  int* rowptr = (int*)(inv + 140000);              // 140004 (per-etype, N_d+1 each)
  int* cursor = rowptr + 140004;                   // 140000
  int* csr = cursor + 140000;                      // 4*800000 = 3.2M ints

  hipMemsetAsync(h1, 0, (size_t)120000 * 128 * 4, stream);
  hipMemsetAsync(h2, 0, (size_t)120000 * 128 * 4, stream);
  hipMemsetAsync(cnt, 0, 140000 * 4, stream);
  hipMemsetAsync(cursor, 0, 140000 * 4, stream);

  const int styp[4] = {0, 0, 1, 2};
  const int dtyp[4] = {2, 1, 2, 0};
  const size_t hoff[3] = {0, 20000, 100000};   // row offsets: drug, gene, disease
  const int coff[4] = {0, 20000, 100000, 120000};
  const int rpoff[4] = {0, 20001, 100002, 120003};
  const int Nn[3] = {20000, 80000, 20000};
  const int Nd[4] = {20000, 80000, 20000, 20000};

  // degree counts (same for both layers) -> inverse, rowptr, CSR
  for (int e = 0; e < 4; ++e)
    count_kernel<<<512, 256, 0, stream>>>(dst[e], cnt + coff[e]);
  inv_kernel<<<(140000 + 255) / 256, 256, 0, stream>>>(cnt, inv, 140000);
  for (int e = 0; e < 4; ++e)
    scan_kernel<<<1, 1024, 0, stream>>>(cnt + coff[e], rowptr + rpoff[e], Nd[e]);
  for (int e = 0; e < 4; ++e)
    place_kernel<<<1024, 256, 0, stream>>>(src[e], dst[e], rowptr + rpoff[e],
                                           cursor + coff[e], csr + (size_t)e * NE);

  // layer 1
  for (int e = 0; e < 4; ++e) {
    int ns = Nn[styp[e]];
    gemm_kernel<false><<<ns / 32, 256, 0, stream>>>(feat[styp[e]], W1[e], b1[e], Wh, ns);
    gather_kernel<<<2048, 256, 0, stream>>>(Wh, csr + (size_t)e * NE, rowptr + rpoff[e],
                                            inv + coff[e], h1 + hoff[dtyp[e]] * 128, Nd[e]);
  }
  // layer 2 (leaky-relu fused into x load)
  for (int e = 0; e < 4; ++e) {
    int ns = Nn[styp[e]];
    gemm_kernel<true><<<ns / 32, 256, 0, stream>>>(h1 + hoff[styp[e]] * 128, W2[e], b2[e], Wh, ns);
    gather_kernel<<<2048, 256, 0, stream>>>(Wh, csr + (size_t)e * NE, rowptr + rpoff[e],
                                            inv + coff[e], h2 + hoff[dtyp[e]] * 128, Nd[e]);
  }
  // scores (pos + neg fused per etype)
  float* out = (float*)d_out;
  for (int e = 0; e < 4; ++e) {
    score_kernel<<<2048, 256, 0, stream>>>(h2 + hoff[styp[e]] * 128, h2 + hoff[dtyp[e]] * 128,
                                           src[e], dst[e], ndst[e], out + (size_t)e * NE,
                                           out + (size_t)(4 + e) * NE);
  }
}

// Round 5
// 1615.234 us; speedup vs baseline: 4.0353x; 1.2880x over previous
//
#include <hip/hip_runtime.h>
#include <hip/hip_bf16.h>
#include <cstddef>

// ---------------- problem constants ----------------
#define NE 800000
// node types: 0=drug, 1=gene, 2=disease
// etypes: 0=treats(drug->disease) 1=targets(drug->gene) 2=assoc(gene->disease) 3=rev_treats(disease->drug)

typedef unsigned short ushortT;

__device__ __forceinline__ float lrelu01(float x) { return x > 0.f ? x : 0.01f * x; }
// bf16 <-> f32 (bf16 as raw ushort bits; b2f exact, f2b round-to-nearest-even)
__device__ __forceinline__ float b2f(ushortT b) { return __uint_as_float(((unsigned)b) << 16); }
__device__ __forceinline__ ushortT f2b(float x) {
  unsigned u = __float_as_uint(x);
  unsigned r = (u + 0x7fffu + ((u >> 16) & 1u)) >> 16;
  return (ushortT)r;
}

// ---------------- degree count (per-etype) ----------------
__global__ __launch_bounds__(256) void count_kernel(const int* __restrict__ dst,
                                                    int* __restrict__ cnt) {
  int stride = gridDim.x * blockDim.x;
  for (int i = blockIdx.x * blockDim.x + threadIdx.x; i < NE; i += stride)
    atomicAdd(&cnt[dst[i]], 1);
}

__global__ __launch_bounds__(256) void inv_kernel(const int* __restrict__ cnt,
                                                  float* __restrict__ inv, int n) {
  int i = blockIdx.x * blockDim.x + threadIdx.x;
  if (i < n) {
    int c = cnt[i];
    inv[i] = 1.0f / (float)(c > 1 ? c : 1);
  }
}

// ---------------- exclusive scan (single workgroup) ----------------
__global__ __launch_bounds__(1024) void scan_kernel(const int* __restrict__ cnt,
                                                    int* __restrict__ rowptr, int n) {
  __shared__ int sums[1024];
  const int tid = threadIdx.x;
  const int per = (n + 1023) >> 10;
  const int beg = tid * per;
  const int end = min(beg + per, n);
  int s = 0;
  for (int i = beg; i < end; ++i) s += cnt[i];
  sums[tid] = s;
  __syncthreads();
  for (int off = 1; off < 1024; off <<= 1) {
    int add = (tid >= off) ? sums[tid - off] : 0;
    __syncthreads();
    sums[tid] += add;
    __syncthreads();
  }
  int run = (tid == 0) ? 0 : sums[tid - 1];
  for (int i = beg; i < end; ++i) {
    rowptr[i] = run;
    run += cnt[i];
  }
  if (tid == 1023) rowptr[n] = sums[1023];
}

// ---------------- CSR placement ----------------
__global__ __launch_bounds__(256) void place_kernel(const int* __restrict__ src,
                                                    const int* __restrict__ dst,
                                                    const int* __restrict__ rowptr,
                                                    int* __restrict__ cursor,
                                                    int* __restrict__ csr) {
  int stride = gridDim.x * blockDim.x;
  for (int i = blockIdx.x * blockDim.x + threadIdx.x; i < NE; i += stride) {
    int d = dst[i];
    int p = rowptr[d] + atomicAdd(&cursor[d], 1);
    csr[p] = src[i];
  }
}

// ---------------- GEMM: out[n,:] = X[n,:] @ W + b  (K=N=128), bf16 output ----------------
template <bool LRELU>
__global__ __launch_bounds__(256) void gemm_kernel(const float* __restrict__ X,
                                                   const float* __restrict__ W,
                                                   const float* __restrict__ bias,
                                                   ushortT* __restrict__ out, int nrows) {
  __shared__ float Ws[128 * 128];
  __shared__ float xs[32 * 128];
  const int tid = threadIdx.x;

  {  // stage W (4096 float4; 16 per thread)
    const float4* Wv = (const float4*)W;
    float4* Wsv = (float4*)Ws;
#pragma unroll
    for (int i = 0; i < 16; ++i) Wsv[tid + 256 * i] = Wv[tid + 256 * i];
  }
  const int row0 = blockIdx.x * 32;
  {  // stage 32 rows of X: 1024 float4; 4 per thread
    float4* xsv = (float4*)xs;
#pragma unroll
    for (int i = 0; i < 4; ++i) {
      int f = tid + 256 * i;
      int rr = f >> 5;
      int c4 = f & 31;
      int gr = row0 + rr;
      float4 v = make_float4(0.f, 0.f, 0.f, 0.f);
      if (gr < nrows) v = *(const float4*)(X + (size_t)gr * 128 + c4 * 4);
      if (LRELU) {
        v.x = lrelu01(v.x); v.y = lrelu01(v.y); v.z = lrelu01(v.z); v.w = lrelu01(v.w);
      }
      xsv[f] = v;
    }
  }
  __syncthreads();

  const int c = tid & 31;
  const int r = tid >> 5;
  const float4 bv = *(const float4*)(bias + c * 4);
  float acc[4][4];
#pragma unroll
  for (int ri = 0; ri < 4; ++ri) {
    acc[ri][0] = bv.x; acc[ri][1] = bv.y; acc[ri][2] = bv.z; acc[ri][3] = bv.w;
  }

#pragma unroll 8
  for (int k0 = 0; k0 < 128; k0 += 4) {
    const float4 w0 = *(const float4*)(Ws + (k0 + 0) * 128 + c * 4);
    const float4 w1 = *(const float4*)(Ws + (k0 + 1) * 128 + c * 4);
    const float4 w2 = *(const float4*)(Ws + (k0 + 2) * 128 + c * 4);
    const float4 w3 = *(const float4*)(Ws + (k0 + 3) * 128 + c * 4);
#pragma unroll
    for (int ri = 0; ri < 4; ++ri) {
      const float4 xv = *(const float4*)(xs + (r + 8 * ri) * 128 + k0);
      acc[ri][0] = fmaf(xv.x, w0.x, acc[ri][0]);
      acc[ri][0] = fmaf(xv.y, w1.x, acc[ri][0]);
      acc[ri][0] = fmaf(xv.z, w2.x, acc[ri][0]);
      acc[ri][0] = fmaf(xv.w, w3.x, acc[ri][0]);
      acc[ri][1] = fmaf(xv.x, w0.y, acc[ri][1]);
      acc[ri][1] = fmaf(xv.y, w1.y, acc[ri][1]);
      acc[ri][1] = fmaf(xv.z, w2.y, acc[ri][1]);
      acc[ri][1] = fmaf(xv.w, w3.y, acc[ri][1]);
      acc[ri][2] = fmaf(xv.x, w0.z, acc[ri][2]);
      acc[ri][2] = fmaf(xv.y, w1.z, acc[ri][2]);
      acc[ri][2] = fmaf(xv.z, w2.z, acc[ri][2]);
      acc[ri][2] = fmaf(xv.w, w3.z, acc[ri][2]);
      acc[ri][3] = fmaf(xv.x, w0.w, acc[ri][3]);
      acc[ri][3] = fmaf(xv.y, w1.w, acc[ri][3]);
      acc[ri][3] = fmaf(xv.z, w2.w, acc[ri][3]);
      acc[ri][3] = fmaf(xv.w, w3.w, acc[ri][3]);
    }
  }

#pragma unroll
  for (int ri = 0; ri < 4; ++ri) {
    int gr = row0 + r + 8 * ri;
    if (gr < nrows) {
      ushort4 o;
      o.x = f2b(acc[ri][0]); o.y = f2b(acc[ri][1]);
      o.z = f2b(acc[ri][2]); o.w = f2b(acc[ri][3]);
      *(ushort4*)(out + (size_t)gr * 128 + c * 4) = o;
    }
  }
}

// ---------------- CSR aggregate: out[d] += inv[d] * sum_{e in row d} Wh[csr[e]] ----------------
// one wave per dst row; half-wave per edge (lane handles 4 bf16 = 8B load)
template <bool OUT_BF16>
__global__ __launch_bounds__(256) void gather_kernel(const ushortT* __restrict__ Wh,
                                                     const int* __restrict__ csr,
                                                     const int* __restrict__ rowptr,
                                                     const float* __restrict__ inv,
                                                     void* __restrict__ outv, int nd) {
  const int lane = threadIdx.x & 63;
  const int half = lane >> 5;
  const int ql = lane & 31;
  int w = (blockIdx.x * blockDim.x + threadIdx.x) >> 6;
  const int nw = (gridDim.x * blockDim.x) >> 6;
  for (int d = w; d < nd; d += nw) {
    const int beg = rowptr[d];
    const int end = rowptr[d + 1];
    float a0 = 0.f, a1 = 0.f, a2 = 0.f, a3 = 0.f;
    for (int c0 = beg; c0 < end; c0 += 64) {
      int m = end - c0;
      if (m > 64) m = 64;
      int idx = (c0 + lane < end) ? csr[c0 + lane] : 0;
      for (int j = 0; j < m; j += 2) {
        int jj = j + half;
        int s = __shfl(idx, jj < m ? jj : 0, 64);
        if (jj < m) {
          ushort4 v = *(const ushort4*)(Wh + (size_t)s * 128 + ql * 4);
          a0 += b2f(v.x); a1 += b2f(v.y); a2 += b2f(v.z); a3 += b2f(v.w);
        }
      }
    }
    // combine the two half-wave partials (alternating edges)
    a0 += __shfl_xor(a0, 32, 64);
    a1 += __shfl_xor(a1, 32, 64);
    a2 += __shfl_xor(a2, 32, 64);
    a3 += __shfl_xor(a3, 32, 64);
    if (lane < 32) {
      float ic = inv[d];
      if (OUT_BF16) {
        ushortT* out = (ushortT*)outv;
        ushort4 o = *(ushort4*)(out + (size_t)d * 128 + ql * 4);
        o.x = f2b(b2f(o.x) + a0 * ic);
        o.y = f2b(b2f(o.y) + a1 * ic);
        o.z = f2b(b2f(o.z) + a2 * ic);
        o.w = f2b(b2f(o.w) + a3 * ic);
        *(ushort4*)(out + (size_t)d * 128 + ql * 4) = o;
      } else {
        float* out = (float*)outv;
        float4 o = *(float4*)(out + (size_t)d * 128 + ql * 4);
        o.x += a0 * ic; o.y += a1 * ic; o.z += a2 * ic; o.w += a3 * ic;
        *(float4*)(out + (size_t)d * 128 + ql * 4) = o;
      }
    }
  }
}

// ---------------- scores: half-wave per edge, bf16 h2 ----------------
__global__ __launch_bounds__(256) void score_kernel(const ushortT* __restrict__ hs,
                                                    const ushortT* __restrict__ hd,
                                                    const int* __restrict__ src,
                                                    const int* __restrict__ dst,
                                                    const int* __restrict__ ndst,
                                                    float* __restrict__ outp,
                                                    float* __restrict__ outn) {
  const int lane = threadIdx.x & 63;
  const int half = lane >> 5;
  const int ql = lane & 31;
  int w = (blockIdx.x * blockDim.x + threadIdx.x) >> 6;
  const int nw = (gridDim.x * blockDim.x) >> 6;
  for (int base = 2 * w; base < NE; base += 2 * nw) {
    int e = base + half;  // NE even -> always valid
    int s = src[e], d = dst[e], n = ndst[e];
    ushort4 av = *(const ushort4*)(hs + (size_t)s * 128 + ql * 4);
    ushort4 bv = *(const ushort4*)(hd + (size_t)d * 128 + ql * 4);
    ushort4 cv = *(const ushort4*)(hd + (size_t)n * 128 + ql * 4);
    float a0 = b2f(av.x), a1 = b2f(av.y), a2 = b2f(av.z), a3 = b2f(av.w);
    float dp = a0 * b2f(bv.x) + a1 * b2f(bv.y) + a2 * b2f(bv.z) + a3 * b2f(bv.w);
    float dn = a0 * b2f(cv.x) + a1 * b2f(cv.y) + a2 * b2f(cv.z) + a3 * b2f(cv.w);
#pragma unroll
    for (int off = 1; off <= 16; off <<= 1) {
      dp += __shfl_xor(dp, off, 64);
      dn += __shfl_xor(dn, off, 64);
    }
    if (ql == 0) {
      outp[e] = 1.0f / (1.0f + expf(-dp));
      outn[e] = 1.0f / (1.0f + expf(-dn));
    }
  }
}

// ---------------- launch ----------------
extern "C" void kernel_launch(void* const* d_in, const int* in_sizes, int n_in,
                              void* d_out, int out_size, void* d_ws, size_t ws_size,
                              hipStream_t stream) {
  const float* feat[3] = {(const float*)d_in[0], (const float*)d_in[1], (const float*)d_in[2]};
  const float *W1[4], *b1[4], *W2[4], *b2[4];
  for (int e = 0; e < 4; ++e) {
    W1[e] = (const float*)d_in[3 + 2 * e];
    b1[e] = (const float*)d_in[4 + 2 * e];
    W2[e] = (const float*)d_in[11 + 2 * e];
    b2[e] = (const float*)d_in[12 + 2 * e];
  }
  const int *src[4], *dst[4], *ndst[4];
  for (int e = 0; e < 4; ++e) {
    src[e] = (const int*)d_in[19 + 3 * e];
    dst[e] = (const int*)d_in[20 + 3 * e];
    ndst[e] = (const int*)d_in[21 + 3 * e];
  }

  // workspace carve-up
  ushortT* Wh = (ushortT*)d_ws;                    // 80000*128 bf16 = 20.5 MB
  float* h1 = (float*)(Wh + (size_t)80000 * 128);  // 120000*128 f32 = 61.4 MB
  ushortT* h2 = (ushortT*)(h1 + (size_t)120000 * 128);  // 120000*128 bf16 = 30.7 MB
  int* cnt = (int*)(h2 + (size_t)120000 * 128);    // 140000
  float* inv = (float*)(cnt + 140000);             // 140000
  int* rowptr = (int*)(inv + 140000);              // 140004
  int* cursor = rowptr + 140004;                   // 140000
  int* csr = cursor + 140000;                      // 3.2M ints

  hipMemsetAsync(h1, 0, (size_t)120000 * 128 * 4, stream);
  hipMemsetAsync(h2, 0, (size_t)120000 * 128 * 2, stream);
  hipMemsetAsync(cnt, 0, 140000 * 4, stream);
  hipMemsetAsync(cursor, 0, 140000 * 4, stream);

  const int styp[4] = {0, 0, 1, 2};
  const int dtyp[4] = {2, 1, 2, 0};
  const size_t hoff[3] = {0, 20000, 100000};   // row offsets: drug, gene, disease
  const int coff[4] = {0, 20000, 100000, 120000};
  const int rpoff[4] = {0, 20001, 100002, 120003};
  const int Nn[3] = {20000, 80000, 20000};
  const int Nd[4] = {20000, 80000, 20000, 20000};

  for (int e = 0; e < 4; ++e)
    count_kernel<<<512, 256, 0, stream>>>(dst[e], cnt + coff[e]);
  inv_kernel<<<(140000 + 255) / 256, 256, 0, stream>>>(cnt, inv, 140000);
  for (int e = 0; e < 4; ++e)
    scan_kernel<<<1, 1024, 0, stream>>>(cnt + coff[e], rowptr + rpoff[e], Nd[e]);
  for (int e = 0; e < 4; ++e)
    place_kernel<<<1024, 256, 0, stream>>>(src[e], dst[e], rowptr + rpoff[e],
                                           cursor + coff[e], csr + (size_t)e * NE);

  // layer 1: GEMM (f32 in, bf16 out) -> gather (bf16 in, f32 out, cross-etype sum)
  for (int e = 0; e < 4; ++e) {
    int ns = Nn[styp[e]];
    gemm_kernel<false><<<ns / 32, 256, 0, stream>>>(feat[styp[e]], W1[e], b1[e], Wh, ns);
    gather_kernel<false><<<2048, 256, 0, stream>>>(Wh, csr + (size_t)e * NE, rowptr + rpoff[e],
                                                   inv + coff[e],
                                                   (void*)(h1 + hoff[dtyp[e]] * 128), Nd[e]);
  }
  // layer 2: GEMM (f32 h1 + lrelu, bf16 out) -> gather (bf16 in, bf16 out)
  for (int e = 0; e < 4; ++e) {
    int ns = Nn[styp[e]];
    gemm_kernel<true><<<ns / 32, 256, 0, stream>>>(h1 + hoff[styp[e]] * 128, W2[e], b2[e], Wh, ns);
    gather_kernel<true><<<2048, 256, 0, stream>>>(Wh, csr + (size_t)e * NE, rowptr + rpoff[e],
                                                  inv + coff[e],
                                                  (void*)(h2 + hoff[dtyp[e]] * 128), Nd[e]);
  }
  // scores (pos + neg fused per etype)
  float* out = (float*)d_out;
  for (int e = 0; e < 4; ++e) {
    score_kernel<<<2048, 256, 0, stream>>>(h2 + hoff[styp[e]] * 128, h2 + hoff[dtyp[e]] * 128,
                                           src[e], dst[e], ndst[e], out + (size_t)e * NE,
                                           out + (size_t)(4 + e) * NE);
  }
}

// Round 6
// 1429.073 us; speedup vs baseline: 4.5610x; 1.1303x over previous
//
#include <hip/hip_runtime.h>
#include <hip/hip_bf16.h>
#include <cstddef>

// ---------------- problem constants ----------------
#define NE 800000
#define NCNT 140000           // total dst-node slots across 4 etypes (20k+80k+20k+20k)
#define NBLK 137              // ceil(140000 / 1024)
// node types: 0=drug, 1=gene, 2=disease
// etypes: 0=treats(drug->disease) 1=targets(drug->gene) 2=assoc(gene->disease) 3=rev_treats(disease->drug)

typedef unsigned short ushortT;

__device__ __forceinline__ float lrelu01(float x) { return x > 0.f ? x : 0.01f * x; }
// bf16 <-> f32 (bf16 as raw ushort bits; b2f exact, f2b round-to-nearest-even)
__device__ __forceinline__ float b2f(ushortT b) { return __uint_as_float(((unsigned)b) << 16); }
__device__ __forceinline__ ushortT f2b(float x) {
  unsigned u = __float_as_uint(x);
  unsigned r = (u + 0x7fffu + ((u >> 16) & 1u)) >> 16;
  return (ushortT)r;
}

// ---------------- degree count (per-etype) ----------------
__global__ __launch_bounds__(256) void count_kernel(const int* __restrict__ dst,
                                                    int* __restrict__ cnt) {
  int stride = gridDim.x * blockDim.x;
  for (int i = blockIdx.x * blockDim.x + threadIdx.x; i < NE; i += stride)
    atomicAdd(&cnt[dst[i]], 1);
}

__global__ __launch_bounds__(256) void inv_kernel(const int* __restrict__ cnt,
                                                  float* __restrict__ inv, int n) {
  int i = blockIdx.x * blockDim.x + threadIdx.x;
  if (i < n) {
    int c = cnt[i];
    inv[i] = 1.0f / (float)(c > 1 ? c : 1);
  }
}

// ---------------- 3-phase grid-wide exclusive scan over cnt[NCNT] ----------------
// P1: per-block (1024 elems) sums
__global__ __launch_bounds__(256) void psum_kernel(const int* __restrict__ cnt,
                                                   int* __restrict__ bsum, int n) {
  __shared__ int red[4];
  const int tid = threadIdx.x;
  const int base = blockIdx.x * 1024;
  int s = 0;
#pragma unroll
  for (int k = 0; k < 4; ++k) {
    int i = base + tid + 256 * k;
    s += (i < n) ? cnt[i] : 0;
  }
#pragma unroll
  for (int off = 32; off >= 1; off >>= 1) s += __shfl_xor(s, off, 64);
  if ((tid & 63) == 0) red[tid >> 6] = s;
  __syncthreads();
  if (tid == 0) bsum[blockIdx.x] = red[0] + red[1] + red[2] + red[3];
}

// P2: exclusive scan of block sums (nb <= 256); also writes gscan[n] = total
__global__ __launch_bounds__(256) void bscan_kernel(const int* __restrict__ bsum,
                                                    int* __restrict__ bex,
                                                    int* __restrict__ gscan, int nb, int n) {
  __shared__ int sh[256];
  const int tid = threadIdx.x;
  sh[tid] = (tid < nb) ? bsum[tid] : 0;
  __syncthreads();
  for (int off = 1; off < 256; off <<= 1) {
    int add = (tid >= off) ? sh[tid - off] : 0;
    __syncthreads();
    sh[tid] += add;
    __syncthreads();
  }
  if (tid < nb) bex[tid] = (tid == 0) ? 0 : sh[tid - 1];
  if (tid == nb - 1) gscan[n] = sh[tid];
}

// P3: per-block exclusive scan + block offset -> gscan[i]
__global__ __launch_bounds__(256) void scanout_kernel(const int* __restrict__ cnt,
                                                      const int* __restrict__ bex,
                                                      int* __restrict__ gscan, int n) {
  __shared__ int part[256];
  const int tid = threadIdx.x;
  const int base = blockIdx.x * 1024 + tid * 4;
  int v0 = (base + 0 < n) ? cnt[base + 0] : 0;
  int v1 = (base + 1 < n) ? cnt[base + 1] : 0;
  int v2 = (base + 2 < n) ? cnt[base + 2] : 0;
  int v3 = (base + 3 < n) ? cnt[base + 3] : 0;
  part[tid] = v0 + v1 + v2 + v3;
  __syncthreads();
  for (int off = 1; off < 256; off <<= 1) {
    int add = (tid >= off) ? part[tid - off] : 0;
    __syncthreads();
    part[tid] += add;
    __syncthreads();
  }
  int ex = bex[blockIdx.x] + ((tid == 0) ? 0 : part[tid - 1]);
  if (base + 0 < n) gscan[base + 0] = ex;
  ex += v0;
  if (base + 1 < n) gscan[base + 1] = ex;
  ex += v1;
  if (base + 2 < n) gscan[base + 2] = ex;
  ex += v2;
  if (base + 3 < n) gscan[base + 3] = ex;
}

// ---------------- CSR placement (rowptr holds GLOBAL csr positions) ----------------
__global__ __launch_bounds__(256) void place_kernel(const int* __restrict__ src,
                                                    const int* __restrict__ dst,
                                                    const int* __restrict__ rowptr,
                                                    int* __restrict__ cursor,
                                                    int* __restrict__ csr) {
  int stride = gridDim.x * blockDim.x;
  for (int i = blockIdx.x * blockDim.x + threadIdx.x; i < NE; i += stride) {
    int d = dst[i];
    int p = rowptr[d] + atomicAdd(&cursor[d], 1);
    csr[p] = src[i];
  }
}

// ---------------- GEMM: out[n,:] = X[n,:] @ W + b  (K=N=128), bf16 output ----------------
template <bool LRELU>
__global__ __launch_bounds__(256) void gemm_kernel(const float* __restrict__ X,
                                                   const float* __restrict__ W,
                                                   const float* __restrict__ bias,
                                                   ushortT* __restrict__ out, int nrows) {
  __shared__ float Ws[128 * 128];
  __shared__ float xs[32 * 128];
  const int tid = threadIdx.x;

  {  // stage W (4096 float4; 16 per thread)
    const float4* Wv = (const float4*)W;
    float4* Wsv = (float4*)Ws;
#pragma unroll
    for (int i = 0; i < 16; ++i) Wsv[tid + 256 * i] = Wv[tid + 256 * i];
  }
  const int row0 = blockIdx.x * 32;
  {  // stage 32 rows of X: 1024 float4; 4 per thread
    float4* xsv = (float4*)xs;
#pragma unroll
    for (int i = 0; i < 4; ++i) {
      int f = tid + 256 * i;
      int rr = f >> 5;
      int c4 = f & 31;
      int gr = row0 + rr;
      float4 v = make_float4(0.f, 0.f, 0.f, 0.f);
      if (gr < nrows) v = *(const float4*)(X + (size_t)gr * 128 + c4 * 4);
      if (LRELU) {
        v.x = lrelu01(v.x); v.y = lrelu01(v.y); v.z = lrelu01(v.z); v.w = lrelu01(v.w);
      }
      xsv[f] = v;
    }
  }
  __syncthreads();

  const int c = tid & 31;
  const int r = tid >> 5;
  const float4 bv = *(const float4*)(bias + c * 4);
  float acc[4][4];
#pragma unroll
  for (int ri = 0; ri < 4; ++ri) {
    acc[ri][0] = bv.x; acc[ri][1] = bv.y; acc[ri][2] = bv.z; acc[ri][3] = bv.w;
  }

#pragma unroll 8
  for (int k0 = 0; k0 < 128; k0 += 4) {
    const float4 w0 = *(const float4*)(Ws + (k0 + 0) * 128 + c * 4);
    const float4 w1 = *(const float4*)(Ws + (k0 + 1) * 128 + c * 4);
    const float4 w2 = *(const float4*)(Ws + (k0 + 2) * 128 + c * 4);
    const float4 w3 = *(const float4*)(Ws + (k0 + 3) * 128 + c * 4);
#pragma unroll
    for (int ri = 0; ri < 4; ++ri) {
      const float4 xv = *(const float4*)(xs + (r + 8 * ri) * 128 + k0);
      acc[ri][0] = fmaf(xv.x, w0.x, acc[ri][0]);
      acc[ri][0] = fmaf(xv.y, w1.x, acc[ri][0]);
      acc[ri][0] = fmaf(xv.z, w2.x, acc[ri][0]);
      acc[ri][0] = fmaf(xv.w, w3.x, acc[ri][0]);
      acc[ri][1] = fmaf(xv.x, w0.y, acc[ri][1]);
      acc[ri][1] = fmaf(xv.y, w1.y, acc[ri][1]);
      acc[ri][1] = fmaf(xv.z, w2.y, acc[ri][1]);
      acc[ri][1] = fmaf(xv.w, w3.y, acc[ri][1]);
      acc[ri][2] = fmaf(xv.x, w0.z, acc[ri][2]);
      acc[ri][2] = fmaf(xv.y, w1.z, acc[ri][2]);
      acc[ri][2] = fmaf(xv.z, w2.z, acc[ri][2]);
      acc[ri][2] = fmaf(xv.w, w3.z, acc[ri][2]);
      acc[ri][3] = fmaf(xv.x, w0.w, acc[ri][3]);
      acc[ri][3] = fmaf(xv.y, w1.w, acc[ri][3]);
      acc[ri][3] = fmaf(xv.z, w2.w, acc[ri][3]);
      acc[ri][3] = fmaf(xv.w, w3.w, acc[ri][3]);
    }
  }

#pragma unroll
  for (int ri = 0; ri < 4; ++ri) {
    int gr = row0 + r + 8 * ri;
    if (gr < nrows) {
      ushort4 o;
      o.x = f2b(acc[ri][0]); o.y = f2b(acc[ri][1]);
      o.z = f2b(acc[ri][2]); o.w = f2b(acc[ri][3]);
      *(ushort4*)(out + (size_t)gr * 128 + c * 4) = o;
    }
  }
}

// ---------------- CSR aggregate: out[d] += inv[d] * sum_{e in row d} Wh[csr[e]] ----------------
// one wave per dst row; half-wave per edge (lane handles 4 bf16 = 8B load)
template <bool OUT_BF16>
__global__ __launch_bounds__(256) void gather_kernel(const ushortT* __restrict__ Wh,
                                                     const int* __restrict__ csr,
                                                     const int* __restrict__ rowptr,
                                                     const float* __restrict__ inv,
                                                     void* __restrict__ outv, int nd) {
  const int lane = threadIdx.x & 63;
  const int half = lane >> 5;
  const int ql = lane & 31;
  int w = (blockIdx.x * blockDim.x + threadIdx.x) >> 6;
  const int nw = (gridDim.x * blockDim.x) >> 6;
  for (int d = w; d < nd; d += nw) {
    const int beg = rowptr[d];
    const int end = rowptr[d + 1];
    float a0 = 0.f, a1 = 0.f, a2 = 0.f, a3 = 0.f;
    for (int c0 = beg; c0 < end; c0 += 64) {
      int m = end - c0;
      if (m > 64) m = 64;
      int idx = (c0 + lane < end) ? csr[c0 + lane] : 0;
      for (int j = 0; j < m; j += 2) {
        int jj = j + half;
        int s = __shfl(idx, jj < m ? jj : 0, 64);
        if (jj < m) {
          ushort4 v = *(const ushort4*)(Wh + (size_t)s * 128 + ql * 4);
          a0 += b2f(v.x); a1 += b2f(v.y); a2 += b2f(v.z); a3 += b2f(v.w);
        }
      }
    }
    // combine the two half-wave partials (alternating edges)
    a0 += __shfl_xor(a0, 32, 64);
    a1 += __shfl_xor(a1, 32, 64);
    a2 += __shfl_xor(a2, 32, 64);
    a3 += __shfl_xor(a3, 32, 64);
    if (lane < 32) {
      float ic = inv[d];
      if (OUT_BF16) {
        ushortT* out = (ushortT*)outv;
        ushort4 o = *(ushort4*)(out + (size_t)d * 128 + ql * 4);
        o.x = f2b(b2f(o.x) + a0 * ic);
        o.y = f2b(b2f(o.y) + a1 * ic);
        o.z = f2b(b2f(o.z) + a2 * ic);
        o.w = f2b(b2f(o.w) + a3 * ic);
        *(ushort4*)(out + (size_t)d * 128 + ql * 4) = o;
      } else {
        float* out = (float*)outv;
        float4 o = *(float4*)(out + (size_t)d * 128 + ql * 4);
        o.x += a0 * ic; o.y += a1 * ic; o.z += a2 * ic; o.w += a3 * ic;
        *(float4*)(out + (size_t)d * 128 + ql * 4) = o;
      }
    }
  }
}

// ---------------- scores: half-wave per edge, bf16 h2 ----------------
__global__ __launch_bounds__(256) void score_kernel(const ushortT* __restrict__ hs,
                                                    const ushortT* __restrict__ hd,
                                                    const int* __restrict__ src,
                                                    const int* __restrict__ dst,
                                                    const int* __restrict__ ndst,
                                                    float* __restrict__ outp,
                                                    float* __restrict__ outn) {
  const int lane = threadIdx.x & 63;
  const int half = lane >> 5;
  const int ql = lane & 31;
  int w = (blockIdx.x * blockDim.x + threadIdx.x) >> 6;
  const int nw = (gridDim.x * blockDim.x) >> 6;
  for (int base = 2 * w; base < NE; base += 2 * nw) {
    int e = base + half;  // NE even -> always valid
    int s = src[e], d = dst[e], n = ndst[e];
    ushort4 av = *(const ushort4*)(hs + (size_t)s * 128 + ql * 4);
    ushort4 bv = *(const ushort4*)(hd + (size_t)d * 128 + ql * 4);
    ushort4 cv = *(const ushort4*)(hd + (size_t)n * 128 + ql * 4);
    float a0 = b2f(av.x), a1 = b2f(av.y), a2 = b2f(av.z), a3 = b2f(av.w);
    float dp = a0 * b2f(bv.x) + a1 * b2f(bv.y) + a2 * b2f(bv.z) + a3 * b2f(bv.w);
    float dn = a0 * b2f(cv.x) + a1 * b2f(cv.y) + a2 * b2f(cv.z) + a3 * b2f(cv.w);
#pragma unroll
    for (int off = 1; off <= 16; off <<= 1) {
      dp += __shfl_xor(dp, off, 64);
      dn += __shfl_xor(dn, off, 64);
    }
    if (ql == 0) {
      outp[e] = 1.0f / (1.0f + expf(-dp));
      outn[e] = 1.0f / (1.0f + expf(-dn));
    }
  }
}

// ---------------- launch ----------------
extern "C" void kernel_launch(void* const* d_in, const int* in_sizes, int n_in,
                              void* d_out, int out_size, void* d_ws, size_t ws_size,
                              hipStream_t stream) {
  const float* feat[3] = {(const float*)d_in[0], (const float*)d_in[1], (const float*)d_in[2]};
  const float *W1[4], *b1[4], *W2[4], *b2[4];
  for (int e = 0; e < 4; ++e) {
    W1[e] = (const float*)d_in[3 + 2 * e];
    b1[e] = (const float*)d_in[4 + 2 * e];
    W2[e] = (const float*)d_in[11 + 2 * e];
    b2[e] = (const float*)d_in[12 + 2 * e];
  }
  const int *src[4], *dst[4], *ndst[4];
  for (int e = 0; e < 4; ++e) {
    src[e] = (const int*)d_in[19 + 3 * e];
    dst[e] = (const int*)d_in[20 + 3 * e];
    ndst[e] = (const int*)d_in[21 + 3 * e];
  }

  // workspace carve-up
  ushortT* Wh = (ushortT*)d_ws;                    // 80000*128 bf16 = 20.5 MB
  float* h1 = (float*)(Wh + (size_t)80000 * 128);  // 120000*128 f32 = 61.4 MB
  ushortT* h2 = (ushortT*)(h1 + (size_t)120000 * 128);  // 120000*128 bf16 = 30.7 MB
  int* cnt = (int*)(h2 + (size_t)120000 * 128);    // NCNT
  float* inv = (float*)(cnt + NCNT);               // NCNT
  int* gscan = (int*)(inv + NCNT);                 // NCNT+1 (global exclusive scan)
  int* cursor = gscan + NCNT + 1;                  // NCNT
  int* bsum = cursor + NCNT;                       // 256
  int* bex = bsum + 256;                           // 256
  int* csr = bex + 256;                            // 3.2M ints (one global buffer)

  hipMemsetAsync(h1, 0, (size_t)120000 * 128 * 4, stream);
  hipMemsetAsync(h2, 0, (size_t)120000 * 128 * 2, stream);
  hipMemsetAsync(cnt, 0, NCNT * 4, stream);
  hipMemsetAsync(cursor, 0, NCNT * 4, stream);

  const int styp[4] = {0, 0, 1, 2};
  const int dtyp[4] = {2, 1, 2, 0};
  const size_t hoff[3] = {0, 20000, 100000};   // row offsets: drug, gene, disease
  const int coff[4] = {0, 20000, 100000, 120000};
  const int Nn[3] = {20000, 80000, 20000};
  const int Nd[4] = {20000, 80000, 20000, 20000};

  for (int e = 0; e < 4; ++e)
    count_kernel<<<512, 256, 0, stream>>>(dst[e], cnt + coff[e]);
  inv_kernel<<<(NCNT + 255) / 256, 256, 0, stream>>>(cnt, inv, NCNT);
  // 3-phase global scan: cnt -> gscan (global CSR positions; etype segments contiguous)
  psum_kernel<<<NBLK, 256, 0, stream>>>(cnt, bsum, NCNT);
  bscan_kernel<<<1, 256, 0, stream>>>(bsum, bex, gscan, NBLK, NCNT);
  scanout_kernel<<<NBLK, 256, 0, stream>>>(cnt, bex, gscan, NCNT);
  for (int e = 0; e < 4; ++e)
    place_kernel<<<1024, 256, 0, stream>>>(src[e], dst[e], gscan + coff[e],
                                           cursor + coff[e], csr);

  // layer 1: GEMM (f32 in, bf16 out) -> gather (bf16 in, f32 out, cross-etype sum)
  for (int e = 0; e < 4; ++e) {
    int ns = Nn[styp[e]];
    gemm_kernel<false><<<ns / 32, 256, 0, stream>>>(feat[styp[e]], W1[e], b1[e], Wh, ns);
    gather_kernel<false><<<2048, 256, 0, stream>>>(Wh, csr, gscan + coff[e],
                                                   inv + coff[e],
                                                   (void*)(h1 + hoff[dtyp[e]] * 128), Nd[e]);
  }
  // layer 2: GEMM (f32 h1 + lrelu, bf16 out) -> gather (bf16 in, bf16 out)
  for (int e = 0; e < 4; ++e) {
    int ns = Nn[styp[e]];
    gemm_kernel<true><<<ns / 32, 256, 0, stream>>>(h1 + hoff[styp[e]] * 128, W2[e], b2[e], Wh, ns);
    gather_kernel<true><<<2048, 256, 0, stream>>>(Wh, csr, gscan + coff[e],
                                                  inv + coff[e],
                                                  (void*)(h2 + hoff[dtyp[e]] * 128), Nd[e]);
  }
  // scores (pos + neg fused per etype)
  float* out = (float*)d_out;
  for (int e = 0; e < 4; ++e) {
    score_kernel<<<2048, 256, 0, stream>>>(h2 + hoff[styp[e]] * 128, h2 + hoff[dtyp[e]] * 128,
                                           src[e], dst[e], ndst[e], out + (size_t)e * NE,
                                           out + (size_t)(4 + e) * NE);
  }
}

// Round 7
// 1095.026 us; speedup vs baseline: 5.9523x; 1.3051x over previous
//
#include <hip/hip_runtime.h>
#include <hip/hip_bf16.h>
#include <cstddef>

// ---------------- problem constants ----------------
#define NE 800000
#define NCNT 140000           // dst-slots across 4 etypes (20k+80k+20k+20k)
#define NBLK 137              // ceil(140000 / 1024)
// node types: 0=drug, 1=gene, 2=disease
// etypes: 0=treats(drug->disease) 1=targets(drug->gene) 2=assoc(gene->disease) 3=rev_treats(disease->drug)
// slot offsets (cnt/inv/gscan): treats 0, targets 20000, assoc 100000, rev_treats 120000
// WhAll row offsets: treats 0, targets 20000, assoc 40000, rev_treats 120000 (140000 rows total)
// h row offsets: drug 0, gene 20000, disease 100000

typedef unsigned short ushortT;

__device__ __forceinline__ float lrelu01(float x) { return x > 0.f ? x : 0.01f * x; }
__device__ __forceinline__ float blo(int v) { return __uint_as_float(((unsigned)v) << 16); }
__device__ __forceinline__ float bhi(int v) { return __uint_as_float(((unsigned)v) & 0xffff0000u); }
__device__ __forceinline__ ushortT f2b(float x) {
  unsigned u = __float_as_uint(x);
  unsigned r = (u + 0x7fffu + ((u >> 16) & 1u)) >> 16;
  return (ushortT)r;
}

// ---------------- degree count: gridDim.y = etype ----------------
__global__ __launch_bounds__(256) void count_kernel(const int* d0, const int* d1,
                                                    const int* d2, const int* d3,
                                                    int* __restrict__ cnt) {
  const int e = blockIdx.y;
  const int* dst = e == 0 ? d0 : e == 1 ? d1 : e == 2 ? d2 : d3;
  int* c = cnt + (e == 0 ? 0 : e == 1 ? 20000 : e == 2 ? 100000 : 120000);
  int stride = gridDim.x * blockDim.x;
  for (int i = blockIdx.x * blockDim.x + threadIdx.x; i < NE; i += stride)
    atomicAdd(&c[dst[i]], 1);
}

__global__ __launch_bounds__(256) void inv_kernel(const int* __restrict__ cnt,
                                                  float* __restrict__ inv, int n) {
  int i = blockIdx.x * blockDim.x + threadIdx.x;
  if (i < n) {
    int c = cnt[i];
    inv[i] = 1.0f / (float)(c > 1 ? c : 1);
  }
}

// ---------------- 3-phase grid-wide exclusive scan over cnt[NCNT] ----------------
__global__ __launch_bounds__(256) void psum_kernel(const int* __restrict__ cnt,
                                                   int* __restrict__ bsum, int n) {
  __shared__ int red[4];
  const int tid = threadIdx.x;
  const int base = blockIdx.x * 1024;
  int s = 0;
#pragma unroll
  for (int k = 0; k < 4; ++k) {
    int i = base + tid + 256 * k;
    s += (i < n) ? cnt[i] : 0;
  }
#pragma unroll
  for (int off = 32; off >= 1; off >>= 1) s += __shfl_xor(s, off, 64);
  if ((tid & 63) == 0) red[tid >> 6] = s;
  __syncthreads();
  if (tid == 0) bsum[blockIdx.x] = red[0] + red[1] + red[2] + red[3];
}

__global__ __launch_bounds__(256) void bscan_kernel(const int* __restrict__ bsum,
                                                    int* __restrict__ bex,
                                                    int* __restrict__ gscan, int nb, int n) {
  __shared__ int sh[256];
  const int tid = threadIdx.x;
  sh[tid] = (tid < nb) ? bsum[tid] : 0;
  __syncthreads();
  for (int off = 1; off < 256; off <<= 1) {
    int add = (tid >= off) ? sh[tid - off] : 0;
    __syncthreads();
    sh[tid] += add;
    __syncthreads();
  }
  if (tid < nb) bex[tid] = (tid == 0) ? 0 : sh[tid - 1];
  if (tid == nb - 1) gscan[n] = sh[tid];
}

__global__ __launch_bounds__(256) void scanout_kernel(const int* __restrict__ cnt,
                                                      const int* __restrict__ bex,
                                                      int* __restrict__ gscan, int n) {
  __shared__ int part[256];
  const int tid = threadIdx.x;
  const int base = blockIdx.x * 1024 + tid * 4;
  int v0 = (base + 0 < n) ? cnt[base + 0] : 0;
  int v1 = (base + 1 < n) ? cnt[base + 1] : 0;
  int v2 = (base + 2 < n) ? cnt[base + 2] : 0;
  int v3 = (base + 3 < n) ? cnt[base + 3] : 0;
  part[tid] = v0 + v1 + v2 + v3;
  __syncthreads();
  for (int off = 1; off < 256; off <<= 1) {
    int add = (tid >= off) ? part[tid - off] : 0;
    __syncthreads();
    part[tid] += add;
    __syncthreads();
  }
  int ex = bex[blockIdx.x] + ((tid == 0) ? 0 : part[tid - 1]);
  if (base + 0 < n) gscan[base + 0] = ex;
  ex += v0;
  if (base + 1 < n) gscan[base + 1] = ex;
  ex += v1;
  if (base + 2 < n) gscan[base + 2] = ex;
  ex += v2;
  if (base + 3 < n) gscan[base + 3] = ex;
}

// ---------------- CSR placement: csr entry = GLOBAL WhAll row; gridDim.y = etype ----------------
__global__ __launch_bounds__(256) void place_kernel(const int* s0, const int* s1,
                                                    const int* s2, const int* s3,
                                                    const int* d0, const int* d1,
                                                    const int* d2, const int* d3,
                                                    const int* __restrict__ gscan,
                                                    int* __restrict__ cursor,
                                                    int* __restrict__ csr) {
  const int e = blockIdx.y;
  const int* src = e == 0 ? s0 : e == 1 ? s1 : e == 2 ? s2 : s3;
  const int* dst = e == 0 ? d0 : e == 1 ? d1 : e == 2 ? d2 : d3;
  const int co = e == 0 ? 0 : e == 1 ? 20000 : e == 2 ? 100000 : 120000;
  const int wr = e == 0 ? 0 : e == 1 ? 20000 : e == 2 ? 40000 : 120000;
  int stride = gridDim.x * blockDim.x;
  for (int i = blockIdx.x * blockDim.x + threadIdx.x; i < NE; i += stride) {
    int d = dst[i];
    int p = gscan[co + d] + atomicAdd(&cursor[co + d], 1);
    csr[p] = src[i] + wr;
  }
}

// ---------------- fused GEMM: WhAll[wo+r,:] = X[r,:] @ W + b (all 4 etypes, 1 dispatch) ----------------
// block = 256 threads, 32 rows. Row counts are exact multiples of 32 -> no bounds checks.
template <bool LRELU>
__global__ __launch_bounds__(256) void gemm_kernel(const float* X0, const float* X1,
                                                   const float* X2, const float* X3,
                                                   const float* W0, const float* W1,
                                                   const float* W2, const float* W3,
                                                   const float* B0, const float* B1,
                                                   const float* B2, const float* B3,
                                                   ushortT* __restrict__ out) {
  __shared__ float Ws[128 * 128];
  __shared__ float xs[32 * 128];
  const int tid = threadIdx.x;
  const int bid = blockIdx.x;

  int lrow0, wo;
  const float *X, *W, *B;
  if (bid < 625)       { lrow0 = bid * 32;          X = X0; W = W0; B = B0; wo = 0; }
  else if (bid < 1250) { lrow0 = (bid - 625) * 32;  X = X1; W = W1; B = B1; wo = 20000; }
  else if (bid < 3750) { lrow0 = (bid - 1250) * 32; X = X2; W = W2; B = B2; wo = 40000; }
  else                 { lrow0 = (bid - 3750) * 32; X = X3; W = W3; B = B3; wo = 120000; }

  {  // stage W (4096 float4; 16 per thread)
    const float4* Wv = (const float4*)W;
    float4* Wsv = (float4*)Ws;
#pragma unroll
    for (int i = 0; i < 16; ++i) Wsv[tid + 256 * i] = Wv[tid + 256 * i];
  }
  {  // stage 32 rows of X: 1024 float4; 4 per thread
    float4* xsv = (float4*)xs;
#pragma unroll
    for (int i = 0; i < 4; ++i) {
      int f = tid + 256 * i;
      int rr = f >> 5;
      int c4 = f & 31;
      float4 v = *(const float4*)(X + (size_t)(lrow0 + rr) * 128 + c4 * 4);
      if (LRELU) {
        v.x = lrelu01(v.x); v.y = lrelu01(v.y); v.z = lrelu01(v.z); v.w = lrelu01(v.w);
      }
      xsv[f] = v;
    }
  }
  __syncthreads();

  const int c = tid & 31;
  const int r = tid >> 5;
  const float4 bv = *(const float4*)(B + c * 4);
  float acc[4][4];
#pragma unroll
  for (int ri = 0; ri < 4; ++ri) {
    acc[ri][0] = bv.x; acc[ri][1] = bv.y; acc[ri][2] = bv.z; acc[ri][3] = bv.w;
  }

#pragma unroll 8
  for (int k0 = 0; k0 < 128; k0 += 4) {
    const float4 w0 = *(const float4*)(Ws + (k0 + 0) * 128 + c * 4);
    const float4 w1 = *(const float4*)(Ws + (k0 + 1) * 128 + c * 4);
    const float4 w2 = *(const float4*)(Ws + (k0 + 2) * 128 + c * 4);
    const float4 w3 = *(const float4*)(Ws + (k0 + 3) * 128 + c * 4);
#pragma unroll
    for (int ri = 0; ri < 4; ++ri) {
      const float4 xv = *(const float4*)(xs + (r + 8 * ri) * 128 + k0);
      acc[ri][0] = fmaf(xv.x, w0.x, acc[ri][0]);
      acc[ri][0] = fmaf(xv.y, w1.x, acc[ri][0]);
      acc[ri][0] = fmaf(xv.z, w2.x, acc[ri][0]);
      acc[ri][0] = fmaf(xv.w, w3.x, acc[ri][0]);
      acc[ri][1] = fmaf(xv.x, w0.y, acc[ri][1]);
      acc[ri][1] = fmaf(xv.y, w1.y, acc[ri][1]);
      acc[ri][1] = fmaf(xv.z, w2.y, acc[ri][1]);
      acc[ri][1] = fmaf(xv.w, w3.y, acc[ri][1]);
      acc[ri][2] = fmaf(xv.x, w0.z, acc[ri][2]);
      acc[ri][2] = fmaf(xv.y, w1.z, acc[ri][2]);
      acc[ri][2] = fmaf(xv.z, w2.z, acc[ri][2]);
      acc[ri][2] = fmaf(xv.w, w3.z, acc[ri][2]);
      acc[ri][3] = fmaf(xv.x, w0.w, acc[ri][3]);
      acc[ri][3] = fmaf(xv.y, w1.w, acc[ri][3]);
      acc[ri][3] = fmaf(xv.z, w2.w, acc[ri][3]);
      acc[ri][3] = fmaf(xv.w, w3.w, acc[ri][3]);
    }
  }

#pragma unroll
  for (int ri = 0; ri < 4; ++ri) {
    int gr = wo + lrow0 + r + 8 * ri;
    ushort4 o;
    o.x = f2b(acc[ri][0]); o.y = f2b(acc[ri][1]);
    o.z = f2b(acc[ri][2]); o.w = f2b(acc[ri][3]);
    *(ushort4*)(out + (size_t)gr * 128 + c * 4) = o;
  }
}

// ---------------- fused CSR aggregate per dst-nodetype ----------------
// one wave per dst NODE; quarter-wave per edge (lane loads int4 = 8 bf16);
// NSLOT incoming etype slot-groups accumulated in registers; single row write (no RMW).
template <bool OUT_BF16, int NSLOT>
__global__ __launch_bounds__(256) void gather_kernel(const ushortT* __restrict__ Wh,
                                                     const int* __restrict__ csr,
                                                     const int* __restrict__ gscan,
                                                     const float* __restrict__ inv,
                                                     int slot0, int slot1,
                                                     void* __restrict__ outv, int nnode) {
  const int lane = threadIdx.x & 63;
  const int q = lane >> 4;
  const int ql = lane & 15;
  int w = (blockIdx.x * blockDim.x + threadIdx.x) >> 6;
  const int nw = (gridDim.x * blockDim.x) >> 6;
  for (int d = w; d < nnode; d += nw) {
    float a0 = 0.f, a1 = 0.f, a2 = 0.f, a3 = 0.f, a4 = 0.f, a5 = 0.f, a6 = 0.f, a7 = 0.f;
#pragma unroll
    for (int k = 0; k < NSLOT; ++k) {
      const int slot = (k == 0 ? slot0 : slot1) + d;
      const int beg = gscan[slot];
      const int end = gscan[slot + 1];
      float t0 = 0.f, t1 = 0.f, t2 = 0.f, t3 = 0.f, t4 = 0.f, t5 = 0.f, t6 = 0.f, t7 = 0.f;
      for (int c0 = beg; c0 < end; c0 += 64) {
        int m = end - c0;
        if (m > 64) m = 64;
        int idx = (c0 + lane < end) ? csr[c0 + lane] : 0;
        for (int j = 0; j < m; j += 4) {
          int jj = j + q;
          int s = __shfl(idx, jj < m ? jj : 0, 64);
          if (jj < m) {
            const int4 v = *(const int4*)(Wh + (size_t)s * 128 + ql * 8);
            t0 += blo(v.x); t1 += bhi(v.x);
            t2 += blo(v.y); t3 += bhi(v.y);
            t4 += blo(v.z); t5 += bhi(v.z);
            t6 += blo(v.w); t7 += bhi(v.w);
          }
        }
      }
      const float ic = inv[slot];
      a0 = fmaf(t0, ic, a0); a1 = fmaf(t1, ic, a1);
      a2 = fmaf(t2, ic, a2); a3 = fmaf(t3, ic, a3);
      a4 = fmaf(t4, ic, a4); a5 = fmaf(t5, ic, a5);
      a6 = fmaf(t6, ic, a6); a7 = fmaf(t7, ic, a7);
    }
    // cross-quarter reduce (xor 16, 32)
    a0 += __shfl_xor(a0, 16, 64); a0 += __shfl_xor(a0, 32, 64);
    a1 += __shfl_xor(a1, 16, 64); a1 += __shfl_xor(a1, 32, 64);
    a2 += __shfl_xor(a2, 16, 64); a2 += __shfl_xor(a2, 32, 64);
    a3 += __shfl_xor(a3, 16, 64); a3 += __shfl_xor(a3, 32, 64);
    a4 += __shfl_xor(a4, 16, 64); a4 += __shfl_xor(a4, 32, 64);
    a5 += __shfl_xor(a5, 16, 64); a5 += __shfl_xor(a5, 32, 64);
    a6 += __shfl_xor(a6, 16, 64); a6 += __shfl_xor(a6, 32, 64);
    a7 += __shfl_xor(a7, 16, 64); a7 += __shfl_xor(a7, 32, 64);
    if (lane < 16) {
      if (OUT_BF16) {
        ushortT* out = (ushortT*)outv;
        int4 o;
        o.x = (int)f2b(a0) | ((int)f2b(a1) << 16);
        o.y = (int)f2b(a2) | ((int)f2b(a3) << 16);
        o.z = (int)f2b(a4) | ((int)f2b(a5) << 16);
        o.w = (int)f2b(a6) | ((int)f2b(a7) << 16);
        *(int4*)(out + (size_t)d * 128 + ql * 8) = o;
      } else {
        float* out = (float*)outv;
        *(float4*)(out + (size_t)d * 128 + ql * 8) = make_float4(a0, a1, a2, a3);
        *(float4*)(out + (size_t)d * 128 + ql * 8 + 4) = make_float4(a4, a5, a6, a7);
      }
    }
  }
}

// ---------------- scores: quarter-wave per edge, bf16 h2, int4 loads ----------------
__global__ __launch_bounds__(256) void score_kernel(const ushortT* __restrict__ hs,
                                                    const ushortT* __restrict__ hd,
                                                    const int* __restrict__ src,
                                                    const int* __restrict__ dst,
                                                    const int* __restrict__ ndst,
                                                    float* __restrict__ outp,
                                                    float* __restrict__ outn) {
  const int lane = threadIdx.x & 63;
  const int q = lane >> 4;
  const int ql = lane & 15;
  int w = (blockIdx.x * blockDim.x + threadIdx.x) >> 6;
  const int nw = (gridDim.x * blockDim.x) >> 6;
  for (int base = 4 * w; base < NE; base += 4 * nw) {
    int e = base + q;  // NE % 4 == 0 -> always valid
    int s = src[e], d = dst[e], n = ndst[e];
    const int4 av = *(const int4*)(hs + (size_t)s * 128 + ql * 8);
    const int4 bv = *(const int4*)(hd + (size_t)d * 128 + ql * 8);
    const int4 cv = *(const int4*)(hd + (size_t)n * 128 + ql * 8);
    float dp = blo(av.x) * blo(bv.x) + bhi(av.x) * bhi(bv.x)
             + blo(av.y) * blo(bv.y) + bhi(av.y) * bhi(bv.y)
             + blo(av.z) * blo(bv.z) + bhi(av.z) * bhi(bv.z)
             + blo(av.w) * blo(bv.w) + bhi(av.w) * bhi(bv.w);
    float dn = blo(av.x) * blo(cv.x) + bhi(av.x) * bhi(cv.x)
             + blo(av.y) * blo(cv.y) + bhi(av.y) * bhi(cv.y)
             + blo(av.z) * blo(cv.z) + bhi(av.z) * bhi(cv.z)
             + blo(av.w) * blo(cv.w) + bhi(av.w) * bhi(cv.w);
#pragma unroll
    for (int off = 1; off <= 8; off <<= 1) {
      dp += __shfl_xor(dp, off, 64);
      dn += __shfl_xor(dn, off, 64);
    }
    if (ql == 0) {
      outp[e] = 1.0f / (1.0f + expf(-dp));
      outn[e] = 1.0f / (1.0f + expf(-dn));
    }
  }
}

// ---------------- launch ----------------
extern "C" void kernel_launch(void* const* d_in, const int* in_sizes, int n_in,
                              void* d_out, int out_size, void* d_ws, size_t ws_size,
                              hipStream_t stream) {
  const float* feat[3] = {(const float*)d_in[0], (const float*)d_in[1], (const float*)d_in[2]};
  const float *W1[4], *b1[4], *W2[4], *b2[4];
  for (int e = 0; e < 4; ++e) {
    W1[e] = (const float*)d_in[3 + 2 * e];
    b1[e] = (const float*)d_in[4 + 2 * e];
    W2[e] = (const float*)d_in[11 + 2 * e];
    b2[e] = (const float*)d_in[12 + 2 * e];
  }
  const int *src[4], *dst[4], *ndst[4];
  for (int e = 0; e < 4; ++e) {
    src[e] = (const int*)d_in[19 + 3 * e];
    dst[e] = (const int*)d_in[20 + 3 * e];
    ndst[e] = (const int*)d_in[21 + 3 * e];
  }

  // workspace carve-up
  ushortT* WhAll = (ushortT*)d_ws;                      // 140000*128 bf16 = 35.84 MB
  float* h1 = (float*)(WhAll + (size_t)140000 * 128);   // 120000*128 f32 = 61.44 MB
  ushortT* h2 = (ushortT*)(h1 + (size_t)120000 * 128);  // 120000*128 bf16 = 30.72 MB
  int* cnt = (int*)(h2 + (size_t)120000 * 128);         // NCNT
  float* inv = (float*)(cnt + NCNT);                    // NCNT
  int* gscan = (int*)(inv + NCNT);                      // NCNT+1
  int* cursor = gscan + NCNT + 1;                       // NCNT
  int* bsum = cursor + NCNT;                            // 256
  int* bex = bsum + 256;                                // 256
  int* csr = bex + 256;                                 // 3.2M ints

  hipMemsetAsync(cnt, 0, NCNT * 4, stream);
  hipMemsetAsync(cursor, 0, NCNT * 4, stream);

  // h row offsets: drug 0, gene 20000, disease 100000
  const size_t HD = 0, HG = 20000, HS = 100000;

  count_kernel<<<dim3(512, 4), 256, 0, stream>>>(dst[0], dst[1], dst[2], dst[3], cnt);
  inv_kernel<<<(NCNT + 255) / 256, 256, 0, stream>>>(cnt, inv, NCNT);
  psum_kernel<<<NBLK, 256, 0, stream>>>(cnt, bsum, NCNT);
  bscan_kernel<<<1, 256, 0, stream>>>(bsum, bex, gscan, NBLK, NCNT);
  scanout_kernel<<<NBLK, 256, 0, stream>>>(cnt, bex, gscan, NCNT);
  place_kernel<<<dim3(512, 4), 256, 0, stream>>>(src[0], src[1], src[2], src[3],
                                                 dst[0], dst[1], dst[2], dst[3],
                                                 gscan, cursor, csr);

  // ---- layer 1 ----
  gemm_kernel<false><<<4375, 256, 0, stream>>>(
      feat[0], feat[0], feat[1], feat[2],
      W1[0], W1[1], W1[2], W1[3], b1[0], b1[1], b1[2], b1[3], WhAll);
  // drug <- rev_treats (slot 120000); gene <- targets (slot 20000);
  // disease <- treats (slot 0) + assoc (slot 100000)
  gather_kernel<false, 1><<<2048, 256, 0, stream>>>(WhAll, csr, gscan, inv, 120000, 0,
                                                    (void*)(h1 + HD * 128), 20000);
  gather_kernel<false, 1><<<2048, 256, 0, stream>>>(WhAll, csr, gscan, inv, 20000, 0,
                                                    (void*)(h1 + HG * 128), 80000);
  gather_kernel<false, 2><<<2048, 256, 0, stream>>>(WhAll, csr, gscan, inv, 0, 100000,
                                                    (void*)(h1 + HS * 128), 20000);

  // ---- layer 2 (leaky-relu fused into GEMM X load) ----
  gemm_kernel<true><<<4375, 256, 0, stream>>>(
      h1 + HD * 128, h1 + HD * 128, h1 + HG * 128, h1 + HS * 128,
      W2[0], W2[1], W2[2], W2[3], b2[0], b2[1], b2[2], b2[3], WhAll);
  gather_kernel<true, 1><<<2048, 256, 0, stream>>>(WhAll, csr, gscan, inv, 120000, 0,
                                                   (void*)(h2 + HD * 128), 20000);
  gather_kernel<true, 1><<<2048, 256, 0, stream>>>(WhAll, csr, gscan, inv, 20000, 0,
                                                   (void*)(h2 + HG * 128), 80000);
  gather_kernel<true, 2><<<2048, 256, 0, stream>>>(WhAll, csr, gscan, inv, 0, 100000,
                                                   (void*)(h2 + HS * 128), 20000);

  // ---- scores (pos + neg fused per etype) ----
  const size_t sh[4] = {HD, HD, HG, HS};   // src nodetype h offset per etype
  const size_t dh[4] = {HS, HG, HS, HD};   // dst nodetype h offset per etype
  float* out = (float*)d_out;
  for (int e = 0; e < 4; ++e) {
    score_kernel<<<2048, 256, 0, stream>>>(h2 + sh[e] * 128, h2 + dh[e] * 128,
                                           src[e], dst[e], ndst[e], out + (size_t)e * NE,
                                           out + (size_t)(4 + e) * NE);
  }
}

// Round 8
// 1092.375 us; speedup vs baseline: 5.9668x; 1.0024x over previous
//
#include <hip/hip_runtime.h>
#include <hip/hip_bf16.h>
#include <cstddef>

// ---------------- problem constants ----------------
#define NE 800000
#define NCNT 140000           // dst-slots across 4 etypes (20k+80k+20k+20k)
#define NBLK 137              // ceil(140000 / 1024)
// node types: 0=drug, 1=gene, 2=disease
// etypes: 0=treats(drug->disease) 1=targets(drug->gene) 2=assoc(gene->disease) 3=rev_treats(disease->drug)
// slot offsets (cnt/inv/gscan/cursor): treats 0, targets 20000, assoc 100000, rev_treats 120000
// WhAll row offsets: treats 0, targets 20000, assoc 40000, rev_treats 120000
// h row offsets: drug 0, gene 20000, disease 100000

typedef unsigned short ushortT;

__device__ __forceinline__ float lrelu01(float x) { return x > 0.f ? x : 0.01f * x; }
__device__ __forceinline__ float blo(int v) { return __uint_as_float(((unsigned)v) << 16); }
__device__ __forceinline__ float bhi(int v) { return __uint_as_float(((unsigned)v) & 0xffff0000u); }
__device__ __forceinline__ ushortT f2b(float x) {
  unsigned u = __float_as_uint(x);
  unsigned r = (u + 0x7fffu + ((u >> 16) & 1u)) >> 16;
  return (ushortT)r;
}

// ---------------- degree count: gridDim.y = etype ----------------
__global__ __launch_bounds__(256) void count_kernel(const int* d0, const int* d1,
                                                    const int* d2, const int* d3,
                                                    int* __restrict__ cnt) {
  const int e = blockIdx.y;
  const int* dst = e == 0 ? d0 : e == 1 ? d1 : e == 2 ? d2 : d3;
  int* c = cnt + (e == 0 ? 0 : e == 1 ? 20000 : e == 2 ? 100000 : 120000);
  int stride = gridDim.x * blockDim.x;
  for (int i = blockIdx.x * blockDim.x + threadIdx.x; i < NE; i += stride)
    atomicAdd(&c[dst[i]], 1);
}

// ---------------- 3-phase grid-wide exclusive scan over cnt[NCNT] ----------------
__global__ __launch_bounds__(256) void psum_kernel(const int* __restrict__ cnt,
                                                   int* __restrict__ bsum, int n) {
  __shared__ int red[4];
  const int tid = threadIdx.x;
  const int base = blockIdx.x * 1024;
  int s = 0;
#pragma unroll
  for (int k = 0; k < 4; ++k) {
    int i = base + tid + 256 * k;
    s += (i < n) ? cnt[i] : 0;
  }
#pragma unroll
  for (int off = 32; off >= 1; off >>= 1) s += __shfl_xor(s, off, 64);
  if ((tid & 63) == 0) red[tid >> 6] = s;
  __syncthreads();
  if (tid == 0) bsum[blockIdx.x] = red[0] + red[1] + red[2] + red[3];
}

__global__ __launch_bounds__(256) void bscan_kernel(const int* __restrict__ bsum,
                                                    int* __restrict__ bex,
                                                    int* __restrict__ gscan, int nb, int n) {
  __shared__ int sh[256];
  const int tid = threadIdx.x;
  sh[tid] = (tid < nb) ? bsum[tid] : 0;
  __syncthreads();
  for (int off = 1; off < 256; off <<= 1) {
    int add = (tid >= off) ? sh[tid - off] : 0;
    __syncthreads();
    sh[tid] += add;
    __syncthreads();
  }
  if (tid < nb) bex[tid] = (tid == 0) ? 0 : sh[tid - 1];
  if (tid == nb - 1) gscan[n] = sh[tid];
}

// P3: per-block scan + offset -> gscan; ALSO cursor=gscan (place's running cursor) and inv
__global__ __launch_bounds__(256) void scanout_kernel(const int* __restrict__ cnt,
                                                      const int* __restrict__ bex,
                                                      int* __restrict__ gscan,
                                                      int* __restrict__ cursor,
                                                      float* __restrict__ inv, int n) {
  __shared__ int part[256];
  const int tid = threadIdx.x;
  const int base = blockIdx.x * 1024 + tid * 4;
  int v0 = (base + 0 < n) ? cnt[base + 0] : 0;
  int v1 = (base + 1 < n) ? cnt[base + 1] : 0;
  int v2 = (base + 2 < n) ? cnt[base + 2] : 0;
  int v3 = (base + 3 < n) ? cnt[base + 3] : 0;
  part[tid] = v0 + v1 + v2 + v3;
  __syncthreads();
  for (int off = 1; off < 256; off <<= 1) {
    int add = (tid >= off) ? part[tid - off] : 0;
    __syncthreads();
    part[tid] += add;
    __syncthreads();
  }
  int ex = bex[blockIdx.x] + ((tid == 0) ? 0 : part[tid - 1]);
  if (base + 0 < n) { gscan[base+0] = ex; cursor[base+0] = ex; inv[base+0] = 1.0f/(float)(v0>1?v0:1); }
  ex += v0;
  if (base + 1 < n) { gscan[base+1] = ex; cursor[base+1] = ex; inv[base+1] = 1.0f/(float)(v1>1?v1:1); }
  ex += v1;
  if (base + 2 < n) { gscan[base+2] = ex; cursor[base+2] = ex; inv[base+2] = 1.0f/(float)(v2>1?v2:1); }
  ex += v2;
  if (base + 3 < n) { gscan[base+3] = ex; cursor[base+3] = ex; inv[base+3] = 1.0f/(float)(v3>1?v3:1); }
}

// ---------------- CSR placement: cursor pre-init to gscan -> 2 random accesses/edge ----------------
__global__ __launch_bounds__(256) void place_kernel(const int* s0, const int* s1,
                                                    const int* s2, const int* s3,
                                                    const int* d0, const int* d1,
                                                    const int* d2, const int* d3,
                                                    int* __restrict__ cursor,
                                                    int* __restrict__ csr) {
  const int e = blockIdx.y;
  const int* src = e == 0 ? s0 : e == 1 ? s1 : e == 2 ? s2 : s3;
  const int* dst = e == 0 ? d0 : e == 1 ? d1 : e == 2 ? d2 : d3;
  const int co = e == 0 ? 0 : e == 1 ? 20000 : e == 2 ? 100000 : 120000;
  const int wr = e == 0 ? 0 : e == 1 ? 20000 : e == 2 ? 40000 : 120000;
  int stride = gridDim.x * blockDim.x;
  for (int i = blockIdx.x * blockDim.x + threadIdx.x; i < NE; i += stride) {
    int p = atomicAdd(&cursor[co + dst[i]], 1);
    csr[p] = src[i] + wr;
  }
}

// ---------------- fused GEMM: WhAll[wo+r,:] = X[r,:] @ W + b (all 4 etypes, 1 dispatch) ----------------
template <bool LRELU, bool XBF16>
__global__ __launch_bounds__(256) void gemm_kernel(const void* X0v, const void* X1v,
                                                   const void* X2v, const void* X3v,
                                                   const float* W0, const float* W1,
                                                   const float* W2, const float* W3,
                                                   const float* B0, const float* B1,
                                                   const float* B2, const float* B3,
                                                   ushortT* __restrict__ out) {
  __shared__ float Ws[128 * 128];
  __shared__ float xs[32 * 128];
  const int tid = threadIdx.x;
  const int bid = blockIdx.x;

  int lrow0, wo;
  const void* Xv;
  const float *W, *B;
  if (bid < 625)       { lrow0 = bid * 32;          Xv = X0v; W = W0; B = B0; wo = 0; }
  else if (bid < 1250) { lrow0 = (bid - 625) * 32;  Xv = X1v; W = W1; B = B1; wo = 20000; }
  else if (bid < 3750) { lrow0 = (bid - 1250) * 32; Xv = X2v; W = W2; B = B2; wo = 40000; }
  else                 { lrow0 = (bid - 3750) * 32; Xv = X3v; W = W3; B = B3; wo = 120000; }

  {  // stage W (4096 float4; 16 per thread)
    const float4* Wv = (const float4*)W;
    float4* Wsv = (float4*)Ws;
#pragma unroll
    for (int i = 0; i < 16; ++i) Wsv[tid + 256 * i] = Wv[tid + 256 * i];
  }
  if (XBF16) {  // stage 32 rows of bf16 X: 512 int4; 2 per thread; unpack+lrelu
    const ushortT* X = (const ushortT*)Xv;
#pragma unroll
    for (int i = 0; i < 2; ++i) {
      int f = tid + 256 * i;          // int4 index 0..511
      int rr = f >> 4;                // row 0..31
      int c8 = f & 15;                // 8-elem group
      int4 v = *(const int4*)(X + (size_t)(lrow0 + rr) * 128 + c8 * 8);
      float x0 = blo(v.x), x1 = bhi(v.x), x2 = blo(v.y), x3 = bhi(v.y);
      float x4 = blo(v.z), x5 = bhi(v.z), x6 = blo(v.w), x7 = bhi(v.w);
      if (LRELU) {
        x0 = lrelu01(x0); x1 = lrelu01(x1); x2 = lrelu01(x2); x3 = lrelu01(x3);
        x4 = lrelu01(x4); x5 = lrelu01(x5); x6 = lrelu01(x6); x7 = lrelu01(x7);
      }
      float* p = xs + rr * 128 + c8 * 8;
      *(float4*)(p) = make_float4(x0, x1, x2, x3);
      *(float4*)(p + 4) = make_float4(x4, x5, x6, x7);
    }
  } else {  // stage f32 X: 1024 float4; 4 per thread
    const float* X = (const float*)Xv;
    float4* xsv = (float4*)xs;
#pragma unroll
    for (int i = 0; i < 4; ++i) {
      int f = tid + 256 * i;
      int rr = f >> 5;
      int c4 = f & 31;
      float4 v = *(const float4*)(X + (size_t)(lrow0 + rr) * 128 + c4 * 4);
      if (LRELU) {
        v.x = lrelu01(v.x); v.y = lrelu01(v.y); v.z = lrelu01(v.z); v.w = lrelu01(v.w);
      }
      xsv[f] = v;
    }
  }
  __syncthreads();

  const int c = tid & 31;
  const int r = tid >> 5;
  const float4 bv = *(const float4*)(B + c * 4);
  float acc[4][4];
#pragma unroll
  for (int ri = 0; ri < 4; ++ri) {
    acc[ri][0] = bv.x; acc[ri][1] = bv.y; acc[ri][2] = bv.z; acc[ri][3] = bv.w;
  }

#pragma unroll 8
  for (int k0 = 0; k0 < 128; k0 += 4) {
    const float4 w0 = *(const float4*)(Ws + (k0 + 0) * 128 + c * 4);
    const float4 w1 = *(const float4*)(Ws + (k0 + 1) * 128 + c * 4);
    const float4 w2 = *(const float4*)(Ws + (k0 + 2) * 128 + c * 4);
    const float4 w3 = *(const float4*)(Ws + (k0 + 3) * 128 + c * 4);
#pragma unroll
    for (int ri = 0; ri < 4; ++ri) {
      const float4 xv = *(const float4*)(xs + (r + 8 * ri) * 128 + k0);
      acc[ri][0] = fmaf(xv.x, w0.x, acc[ri][0]);
      acc[ri][0] = fmaf(xv.y, w1.x, acc[ri][0]);
      acc[ri][0] = fmaf(xv.z, w2.x, acc[ri][0]);
      acc[ri][0] = fmaf(xv.w, w3.x, acc[ri][0]);
      acc[ri][1] = fmaf(xv.x, w0.y, acc[ri][1]);
      acc[ri][1] = fmaf(xv.y, w1.y, acc[ri][1]);
      acc[ri][1] = fmaf(xv.z, w2.y, acc[ri][1]);
      acc[ri][1] = fmaf(xv.w, w3.y, acc[ri][1]);
      acc[ri][2] = fmaf(xv.x, w0.z, acc[ri][2]);
      acc[ri][2] = fmaf(xv.y, w1.z, acc[ri][2]);
      acc[ri][2] = fmaf(xv.z, w2.z, acc[ri][2]);
      acc[ri][2] = fmaf(xv.w, w3.z, acc[ri][2]);
      acc[ri][3] = fmaf(xv.x, w0.w, acc[ri][3]);
      acc[ri][3] = fmaf(xv.y, w1.w, acc[ri][3]);
      acc[ri][3] = fmaf(xv.z, w2.w, acc[ri][3]);
      acc[ri][3] = fmaf(xv.w, w3.w, acc[ri][3]);
    }
  }

#pragma unroll
  for (int ri = 0; ri < 4; ++ri) {
    int gr = wo + lrow0 + r + 8 * ri;
    ushort4 o;
    o.x = f2b(acc[ri][0]); o.y = f2b(acc[ri][1]);
    o.z = f2b(acc[ri][2]); o.w = f2b(acc[ri][3]);
    *(ushort4*)(out + (size_t)gr * 128 + c * 4) = o;
  }
}

// ---------------- fused CSR aggregate per dst-nodetype ----------------
// QUARTER-WAVE (16 lanes) per dst node: 4 rows/wave, no cross-lane reduce,
// 4 edge-rows loaded before accumulating (branch-free masked tail) -> 4x MLP.
template <int NSLOT>
__global__ __launch_bounds__(256) void gather_kernel(const ushortT* __restrict__ Wh,
                                                     const int* __restrict__ csr,
                                                     const int* __restrict__ gscan,
                                                     const float* __restrict__ inv,
                                                     int slot0, int slot1,
                                                     ushortT* __restrict__ out, int nnode) {
  const int lane = threadIdx.x & 63;
  const int ql = lane & 15;
  const int qbase = lane & 48;  // 16*(lane>>4)
  const int d = (blockIdx.x * blockDim.x + threadIdx.x) >> 4;
  if (d >= nnode) return;
  float a0 = 0.f, a1 = 0.f, a2 = 0.f, a3 = 0.f, a4 = 0.f, a5 = 0.f, a6 = 0.f, a7 = 0.f;
#pragma unroll
  for (int k = 0; k < NSLOT; ++k) {
    const int slot = (k == 0 ? slot0 : slot1) + d;
    const int beg = gscan[slot];
    const int end = gscan[slot + 1];
    float t0 = 0.f, t1 = 0.f, t2 = 0.f, t3 = 0.f, t4 = 0.f, t5 = 0.f, t6 = 0.f, t7 = 0.f;
    for (int c0 = beg; c0 < end; c0 += 16) {
      int m = end - c0;
      if (m > 16) m = 16;
      int idx = (c0 + ql < end) ? csr[c0 + ql] : 0;
      for (int j = 0; j < m; j += 4) {  // j in {0,4,8,12} -> qbase+j+3 <= 15 in-quarter
        int s0 = __shfl(idx, qbase + j, 64);
        int s1 = __shfl(idx, qbase + j + 1, 64);
        int s2 = __shfl(idx, qbase + j + 2, 64);
        int s3 = __shfl(idx, qbase + j + 3, 64);
        const int4 v0 = *(const int4*)(Wh + (size_t)s0 * 128 + ql * 8);
        const int4 v1 = *(const int4*)(Wh + (size_t)s1 * 128 + ql * 8);
        const int4 v2 = *(const int4*)(Wh + (size_t)s2 * 128 + ql * 8);
        const int4 v3 = *(const int4*)(Wh + (size_t)s3 * 128 + ql * 8);
        const float w1 = (j + 1 < m) ? 1.f : 0.f;
        const float w2 = (j + 2 < m) ? 1.f : 0.f;
        const float w3 = (j + 3 < m) ? 1.f : 0.f;
        t0 += blo(v0.x); t0 = fmaf(w1, blo(v1.x), t0); t0 = fmaf(w2, blo(v2.x), t0); t0 = fmaf(w3, blo(v3.x), t0);
        t1 += bhi(v0.x); t1 = fmaf(w1, bhi(v1.x), t1); t1 = fmaf(w2, bhi(v2.x), t1); t1 = fmaf(w3, bhi(v3.x), t1);
        t2 += blo(v0.y); t2 = fmaf(w1, blo(v1.y), t2); t2 = fmaf(w2, blo(v2.y), t2); t2 = fmaf(w3, blo(v3.y), t2);
        t3 += bhi(v0.y); t3 = fmaf(w1, bhi(v1.y), t3); t3 = fmaf(w2, bhi(v2.y), t3); t3 = fmaf(w3, bhi(v3.y), t3);
        t4 += blo(v0.z); t4 = fmaf(w1, blo(v1.z), t4); t4 = fmaf(w2, blo(v2.z), t4); t4 = fmaf(w3, blo(v3.z), t4);
        t5 += bhi(v0.z); t5 = fmaf(w1, bhi(v1.z), t5); t5 = fmaf(w2, bhi(v2.z), t5); t5 = fmaf(w3, bhi(v3.z), t5);
        t6 += blo(v0.w); t6 = fmaf(w1, blo(v1.w), t6); t6 = fmaf(w2, blo(v2.w), t6); t6 = fmaf(w3, blo(v3.w), t6);
        t7 += bhi(v0.w); t7 = fmaf(w1, bhi(v1.w), t7); t7 = fmaf(w2, bhi(v2.w), t7); t7 = fmaf(w3, bhi(v3.w), t7);
      }
    }
    const float ic = inv[slot];
    a0 = fmaf(t0, ic, a0); a1 = fmaf(t1, ic, a1);
    a2 = fmaf(t2, ic, a2); a3 = fmaf(t3, ic, a3);
    a4 = fmaf(t4, ic, a4); a5 = fmaf(t5, ic, a5);
    a6 = fmaf(t6, ic, a6); a7 = fmaf(t7, ic, a7);
  }
  int4 o;
  o.x = (int)f2b(a0) | ((int)f2b(a1) << 16);
  o.y = (int)f2b(a2) | ((int)f2b(a3) << 16);
  o.z = (int)f2b(a4) | ((int)f2b(a5) << 16);
  o.w = (int)f2b(a6) | ((int)f2b(a7) << 16);
  *(int4*)(out + (size_t)d * 128 + ql * 8) = o;
}

// ---------------- scores: 8 edges/wave (2 per quarter), bf16 h2, int4 loads ----------------
__global__ __launch_bounds__(256) void score_kernel(const ushortT* __restrict__ hs,
                                                    const ushortT* __restrict__ hd,
                                                    const int* __restrict__ src,
                                                    const int* __restrict__ dst,
                                                    const int* __restrict__ ndst,
                                                    float* __restrict__ outp,
                                                    float* __restrict__ outn) {
  const int lane = threadIdx.x & 63;
  const int q = lane >> 4;
  const int ql = lane & 15;
  int w = (blockIdx.x * blockDim.x + threadIdx.x) >> 6;
  const int nw = (gridDim.x * blockDim.x) >> 6;
  for (int base = 8 * w; base < NE; base += 8 * nw) {
    int e1 = base + q;       // NE % 8 == 0 -> always valid
    int e2 = base + 4 + q;
    int s1 = src[e1], d1 = dst[e1], n1 = ndst[e1];
    int s2 = src[e2], d2 = dst[e2], n2 = ndst[e2];
    const int4 av1 = *(const int4*)(hs + (size_t)s1 * 128 + ql * 8);
    const int4 bv1 = *(const int4*)(hd + (size_t)d1 * 128 + ql * 8);
    const int4 cv1 = *(const int4*)(hd + (size_t)n1 * 128 + ql * 8);
    const int4 av2 = *(const int4*)(hs + (size_t)s2 * 128 + ql * 8);
    const int4 bv2 = *(const int4*)(hd + (size_t)d2 * 128 + ql * 8);
    const int4 cv2 = *(const int4*)(hd + (size_t)n2 * 128 + ql * 8);
    float dp1 = blo(av1.x) * blo(bv1.x) + bhi(av1.x) * bhi(bv1.x)
              + blo(av1.y) * blo(bv1.y) + bhi(av1.y) * bhi(bv1.y)
              + blo(av1.z) * blo(bv1.z) + bhi(av1.z) * bhi(bv1.z)
              + blo(av1.w) * blo(bv1.w) + bhi(av1.w) * bhi(bv1.w);
    float dn1 = blo(av1.x) * blo(cv1.x) + bhi(av1.x) * bhi(cv1.x)
              + blo(av1.y) * blo(cv1.y) + bhi(av1.y) * bhi(cv1.y)
              + blo(av1.z) * blo(cv1.z) + bhi(av1.z) * bhi(cv1.z)
              + blo(av1.w) * blo(cv1.w) + bhi(av1.w) * bhi(cv1.w);
    float dp2 = blo(av2.x) * blo(bv2.x) + bhi(av2.x) * bhi(bv2.x)
              + blo(av2.y) * blo(bv2.y) + bhi(av2.y) * bhi(bv2.y)
              + blo(av2.z) * blo(bv2.z) + bhi(av2.z) * bhi(bv2.z)
              + blo(av2.w) * blo(bv2.w) + bhi(av2.w) * bhi(bv2.w);
    float dn2 = blo(av2.x) * blo(cv2.x) + bhi(av2.x) * bhi(cv2.x)
              + blo(av2.y) * blo(cv2.y) + bhi(av2.y) * bhi(cv2.y)
              + blo(av2.z) * blo(cv2.z) + bhi(av2.z) * bhi(cv2.z)
              + blo(av2.w) * blo(cv2.w) + bhi(av2.w) * bhi(cv2.w);
#pragma unroll
    for (int off = 1; off <= 8; off <<= 1) {
      dp1 += __shfl_xor(dp1, off, 64);
      dn1 += __shfl_xor(dn1, off, 64);
      dp2 += __shfl_xor(dp2, off, 64);
      dn2 += __shfl_xor(dn2, off, 64);
    }
    if (ql == 0) {
      outp[e1] = 1.0f / (1.0f + expf(-dp1));
      outn[e1] = 1.0f / (1.0f + expf(-dn1));
      outp[e2] = 1.0f / (1.0f + expf(-dp2));
      outn[e2] = 1.0f / (1.0f + expf(-dn2));
    }
  }
}

// ---------------- launch ----------------
extern "C" void kernel_launch(void* const* d_in, const int* in_sizes, int n_in,
                              void* d_out, int out_size, void* d_ws, size_t ws_size,
                              hipStream_t stream) {
  const float* feat[3] = {(const float*)d_in[0], (const float*)d_in[1], (const float*)d_in[2]};
  const float *W1[4], *b1[4], *W2[4], *b2[4];
  for (int e = 0; e < 4; ++e) {
    W1[e] = (const float*)d_in[3 + 2 * e];
    b1[e] = (const float*)d_in[4 + 2 * e];
    W2[e] = (const float*)d_in[11 + 2 * e];
    b2[e] = (const float*)d_in[12 + 2 * e];
  }
  const int *src[4], *dst[4], *ndst[4];
  for (int e = 0; e < 4; ++e) {
    src[e] = (const int*)d_in[19 + 3 * e];
    dst[e] = (const int*)d_in[20 + 3 * e];
    ndst[e] = (const int*)d_in[21 + 3 * e];
  }

  // workspace carve-up (all h buffers bf16 now)
  ushortT* WhAll = (ushortT*)d_ws;                       // 140000*128 bf16 = 35.8 MB
  ushortT* h1 = WhAll + (size_t)140000 * 128;            // 120000*128 bf16 = 30.7 MB
  ushortT* h2 = h1 + (size_t)120000 * 128;               // 30.7 MB
  int* cnt = (int*)(h2 + (size_t)120000 * 128);          // NCNT
  float* inv = (float*)(cnt + NCNT);                     // NCNT
  int* gscan = (int*)(inv + NCNT);                       // NCNT+1
  int* cursor = gscan + NCNT + 1;                        // NCNT
  int* bsum = cursor + NCNT;                             // 256
  int* bex = bsum + 256;                                 // 256
  int* csr = bex + 256;                                  // 3.2M ints

  hipMemsetAsync(cnt, 0, NCNT * 4, stream);

  // h row offsets: drug 0, gene 20000, disease 100000
  const size_t HD = 0, HG = 20000, HS = 100000;

  count_kernel<<<dim3(512, 4), 256, 0, stream>>>(dst[0], dst[1], dst[2], dst[3], cnt);
  psum_kernel<<<NBLK, 256, 0, stream>>>(cnt, bsum, NCNT);
  bscan_kernel<<<1, 256, 0, stream>>>(bsum, bex, gscan, NBLK, NCNT);
  scanout_kernel<<<NBLK, 256, 0, stream>>>(cnt, bex, gscan, cursor, inv, NCNT);
  place_kernel<<<dim3(512, 4), 256, 0, stream>>>(src[0], src[1], src[2], src[3],
                                                 dst[0], dst[1], dst[2], dst[3],
                                                 cursor, csr);

  // ---- layer 1 (f32 feats in) ----
  gemm_kernel<false, false><<<4375, 256, 0, stream>>>(
      feat[0], feat[0], feat[1], feat[2],
      W1[0], W1[1], W1[2], W1[3], b1[0], b1[1], b1[2], b1[3], WhAll);
  // drug <- rev_treats (slot 120000); gene <- targets (20000); disease <- treats (0) + assoc (100000)
  gather_kernel<1><<<1250, 256, 0, stream>>>(WhAll, csr, gscan, inv, 120000, 0, h1 + HD * 128, 20000);
  gather_kernel<1><<<5000, 256, 0, stream>>>(WhAll, csr, gscan, inv, 20000, 0, h1 + HG * 128, 80000);
  gather_kernel<2><<<1250, 256, 0, stream>>>(WhAll, csr, gscan, inv, 0, 100000, h1 + HS * 128, 20000);

  // ---- layer 2 (bf16 h1 in, leaky-relu fused into staging) ----
  gemm_kernel<true, true><<<4375, 256, 0, stream>>>(
      h1 + HD * 128, h1 + HD * 128, h1 + HG * 128, h1 + HS * 128,
      W2[0], W2[1], W2[2], W2[3], b2[0], b2[1], b2[2], b2[3], WhAll);
  gather_kernel<1><<<1250, 256, 0, stream>>>(WhAll, csr, gscan, inv, 120000, 0, h2 + HD * 128, 20000);
  gather_kernel<1><<<5000, 256, 0, stream>>>(WhAll, csr, gscan, inv, 20000, 0, h2 + HG * 128, 80000);
  gather_kernel<2><<<1250, 256, 0, stream>>>(WhAll, csr, gscan, inv, 0, 100000, h2 + HS * 128, 20000);

  // ---- scores (pos + neg fused per etype) ----
  const size_t sh[4] = {HD, HD, HG, HS};   // src nodetype h offset per etype
  const size_t dh[4] = {HS, HG, HS, HD};   // dst nodetype h offset per etype
  float* out = (float*)d_out;
  for (int e = 0; e < 4; ++e) {
    score_kernel<<<2048, 256, 0, stream>>>(h2 + sh[e] * 128, h2 + dh[e] * 128,
                                           src[e], dst[e], ndst[e], out + (size_t)e * NE,
                                           out + (size_t)(4 + e) * NE);
  }
}